// Round 1
// baseline (984.830 us; speedup 1.0000x reference)
//
#include <hip/hip_runtime.h>
#include <hip/hip_bf16.h>
#include <cstdint>

typedef __attribute__((ext_vector_type(8))) short short8;
typedef __attribute__((ext_vector_type(4))) float f32x4;
typedef unsigned short u16;
typedef unsigned int u32;

#define Mdim 1024
#define Ddim 768
#define Edim 100
#define BM 128
#define BN 128
#define BK 32
#define SK 40   // padded LDS stride in bf16 elems (80B rows -> 2-way bank alias = free)

__device__ __forceinline__ u16 f2bf(float f) {
  u32 u = __builtin_bit_cast(u32, f);
  u += 0x7fffu + ((u >> 16) & 1u);   // RNE
  return (u16)(u >> 16);
}
__device__ __forceinline__ float bf2f(u16 h) {
  return __builtin_bit_cast(float, ((u32)h) << 16);
}
__device__ __forceinline__ u32 pack2(float a, float b) {
  return (u32)f2bf(a) | ((u32)f2bf(b) << 16);
}

// ---------------- x: f32 -> bf16 ----------------
__global__ void k_cvt(const float* __restrict__ x, u16* __restrict__ xb) {
  size_t i = ((size_t)blockIdx.x * 256 + threadIdx.x) * 4;
  float4 v = *(const float4*)(x + i);
  uint2 r;
  r.x = pack2(v.x, v.y);
  r.y = pack2(v.z, v.w);
  *(uint2*)(xb + i) = r;
}

// ---------------- kernel A: h = gelu(x @ w1^T + b1), per expert ----------------
__global__ __launch_bounds__(256)
void k_h(const u16* __restrict__ xb, const float* __restrict__ w1,
         const float* __restrict__ b1, u16* __restrict__ hout, int e_base) {
  __shared__ __align__(16) u16 As[BM * SK];
  __shared__ __align__(16) u16 Bs[BN * SK];
  const int bid = blockIdx.x;
  const int el = bid / 48;
  const int e = e_base + el;
  const int r = bid % 48;
  const int m0 = (r / 6) * BM, n0 = (r % 6) * BN;
  const float* W = w1 + (size_t)e * Ddim * Ddim;
  const int t = threadIdx.x;
  const int lane = t & 63;
  const int wv = t >> 6;
  const int wr = (wv >> 1) * 64, wc = (wv & 1) * 64;
  const int lrow = lane & 15, lk = (lane >> 4) << 3;
  const int srow = t >> 2, skc = (t & 3) << 3;

  f32x4 acc[4][4] = {};
  for (int kt = 0; kt < Ddim; kt += BK) {
#pragma unroll
    for (int i = 0; i < 2; ++i) {
      const int row = srow + i * 64;
      uint4 va = *(const uint4*)(xb + (size_t)(m0 + row) * Ddim + kt + skc);
      *(uint4*)(&As[row * SK + skc]) = va;
      const float4 f0 = *(const float4*)(W + (size_t)(n0 + row) * Ddim + kt + skc);
      const float4 f1 = *(const float4*)(W + (size_t)(n0 + row) * Ddim + kt + skc + 4);
      uint4 vb;
      vb.x = pack2(f0.x, f0.y); vb.y = pack2(f0.z, f0.w);
      vb.z = pack2(f1.x, f1.y); vb.w = pack2(f1.z, f1.w);
      *(uint4*)(&Bs[row * SK + skc]) = vb;
    }
    __syncthreads();
    short8 af[4], bfr[4];
#pragma unroll
    for (int f = 0; f < 4; ++f) {
      af[f]  = *(const short8*)(&As[(wr + f * 16 + lrow) * SK + lk]);
      bfr[f] = *(const short8*)(&Bs[(wc + f * 16 + lrow) * SK + lk]);
    }
#pragma unroll
    for (int fm = 0; fm < 4; ++fm)
#pragma unroll
      for (int fn = 0; fn < 4; ++fn)
        acc[fm][fn] = __builtin_amdgcn_mfma_f32_16x16x32_bf16(af[fm], bfr[fn], acc[fm][fn], 0, 0, 0);
    __syncthreads();
  }
  const float* bias = b1 + (size_t)e * Ddim + n0;
  u16* hb = hout + (size_t)el * Mdim * Ddim;
#pragma unroll
  for (int fm = 0; fm < 4; ++fm) {
    const int mb = m0 + wr + fm * 16 + ((lane >> 4) << 2);
#pragma unroll
    for (int fn = 0; fn < 4; ++fn) {
      const int nc = wc + fn * 16 + lrow;
      const float bv = bias[nc];
#pragma unroll
      for (int j = 0; j < 4; ++j) {
        float v = acc[fm][fn][j] + bv;
        v = 0.5f * v * (1.0f + erff(v * 0.7071067811865475f));
        hb[(size_t)(mb + j) * Ddim + n0 + nc] = f2bf(v);
      }
    }
  }
}

// ---------------- kernel B: out_e = x @ w_lin^T + h @ w2^T + b_lin + b2 ----------------
// OUTMODE: 0 = bf16 ws tile [e][m][o], 1 = f32 ws tile, 2 = direct strided f32 to d_out
template <int OUTMODE>
__global__ __launch_bounds__(256)
void k_out(const u16* __restrict__ xb, const u16* __restrict__ hbuf,
           const float* __restrict__ w_lin, const float* __restrict__ b_lin,
           const float* __restrict__ w2, const float* __restrict__ b2,
           void* __restrict__ tout, float* __restrict__ out, int e_base) {
  __shared__ __align__(16) u16 As[BM * SK];
  __shared__ __align__(16) u16 Bs[BN * SK];
  const int bid = blockIdx.x;
  const int el = bid / 48;
  const int e = e_base + el;
  const int r = bid % 48;
  const int m0 = (r / 6) * BM, n0 = (r % 6) * BN;
  const int t = threadIdx.x;
  const int lane = t & 63;
  const int wv = t >> 6;
  const int wr = (wv >> 1) * 64, wc = (wv & 1) * 64;
  const int lrow = lane & 15, lk = (lane >> 4) << 3;
  const int srow = t >> 2, skc = (t & 3) << 3;

  f32x4 acc[4][4] = {};
#pragma unroll
  for (int ph = 0; ph < 2; ++ph) {
    const u16* A = ph ? (hbuf + (size_t)el * Mdim * Ddim) : xb;
    const float* W = (ph ? w2 : w_lin) + (size_t)e * Ddim * Ddim;
    for (int kt = 0; kt < Ddim; kt += BK) {
#pragma unroll
      for (int i = 0; i < 2; ++i) {
        const int row = srow + i * 64;
        uint4 va = *(const uint4*)(A + (size_t)(m0 + row) * Ddim + kt + skc);
        *(uint4*)(&As[row * SK + skc]) = va;
        const float4 f0 = *(const float4*)(W + (size_t)(n0 + row) * Ddim + kt + skc);
        const float4 f1 = *(const float4*)(W + (size_t)(n0 + row) * Ddim + kt + skc + 4);
        uint4 vb;
        vb.x = pack2(f0.x, f0.y); vb.y = pack2(f0.z, f0.w);
        vb.z = pack2(f1.x, f1.y); vb.w = pack2(f1.z, f1.w);
        *(uint4*)(&Bs[row * SK + skc]) = vb;
      }
      __syncthreads();
      short8 af[4], bfr[4];
#pragma unroll
      for (int f = 0; f < 4; ++f) {
        af[f]  = *(const short8*)(&As[(wr + f * 16 + lrow) * SK + lk]);
        bfr[f] = *(const short8*)(&Bs[(wc + f * 16 + lrow) * SK + lk]);
      }
#pragma unroll
      for (int fm = 0; fm < 4; ++fm)
#pragma unroll
        for (int fn = 0; fn < 4; ++fn)
          acc[fm][fn] = __builtin_amdgcn_mfma_f32_16x16x32_bf16(af[fm], bfr[fn], acc[fm][fn], 0, 0, 0);
      __syncthreads();
    }
  }
  const float* bl = b_lin + (size_t)e * Ddim + n0;
  const float* bm = b2 + (size_t)e * Ddim + n0;
#pragma unroll
  for (int fm = 0; fm < 4; ++fm) {
    const int mb = m0 + wr + fm * 16 + ((lane >> 4) << 2);
#pragma unroll
    for (int fn = 0; fn < 4; ++fn) {
      const int nc = wc + fn * 16 + lrow;
      const float bv = bl[nc] + bm[nc];
#pragma unroll
      for (int j = 0; j < 4; ++j) {
        float v = acc[fm][fn][j] + bv;
        if (OUTMODE == 0) {
          ((u16*)tout)[((size_t)e * Mdim + mb + j) * Ddim + n0 + nc] = f2bf(v);
        } else if (OUTMODE == 1) {
          ((float*)tout)[((size_t)e * Mdim + mb + j) * Ddim + n0 + nc] = v;
        } else {
          out[((size_t)(mb + j) * Ddim + n0 + nc) * Edim + e] = v;
        }
      }
    }
  }
}

// ---------------- transpose [E][M*D] -> [M*D][E] ----------------
__global__ __launch_bounds__(256)
void k_tr_f32(const float* __restrict__ tbuf, float* __restrict__ out) {
  __shared__ __align__(16) float tile[100 * 130];  // md-chunk 128, stride 130
  const int t = threadIdx.x;
  const size_t MD = (size_t)Mdim * Ddim;
  const size_t md0 = (size_t)blockIdx.x * 128;
#pragma unroll
  for (int p = 0; p < 25; ++p) {
    const int e = p * 4 + (t >> 6);
    const int c = (t & 63) * 2;
    float2 v = *(const float2*)(tbuf + (size_t)e * MD + md0 + c);
    *(float2*)(&tile[e * 130 + c]) = v;
  }
  __syncthreads();
  const size_t obase = md0 * 100;
#pragma unroll 5
  for (int i = 0; i < 50; ++i) {
    const int flat = t + i * 256;            // < 12800
    const int mo = (int)(((u32)flat * 5243u) >> 19);   // /100
    const int e = flat - mo * 100;
    out[obase + flat] = tile[e * 130 + mo];
  }
}

__global__ __launch_bounds__(256)
void k_tr_bf(const u16* __restrict__ tbuf, float* __restrict__ out) {
  __shared__ __align__(16) u16 tile[100 * 260];  // md-chunk 256, stride 260
  const int t = threadIdx.x;
  const size_t MD = (size_t)Mdim * Ddim;
  const size_t md0 = (size_t)blockIdx.x * 256;
#pragma unroll
  for (int p = 0; p < 25; ++p) {
    const int e = p * 4 + (t >> 6);
    const int c = (t & 63) * 4;
    uint2 v = *(const uint2*)(tbuf + (size_t)e * MD + md0 + c);
    *(uint2*)(&tile[e * 260 + c]) = v;
  }
  __syncthreads();
  const size_t obase = md0 * 100;
#pragma unroll 5
  for (int i = 0; i < 100; ++i) {
    const int flat = t + i * 256;            // < 25600
    const int mo = (int)(((u32)flat * 5243u) >> 19);   // /100
    const int e = flat - mo * 100;
    out[obase + flat] = bf2f(tile[e * 260 + mo]);
  }
}

extern "C" void kernel_launch(void* const* d_in, const int* in_sizes, int n_in,
                              void* d_out, int out_size, void* d_ws, size_t ws_size,
                              hipStream_t stream) {
  const float* x     = (const float*)d_in[0];
  const float* w_lin = (const float*)d_in[1];
  const float* b_lin = (const float*)d_in[2];
  const float* w1    = (const float*)d_in[3];
  const float* b1    = (const float*)d_in[4];
  const float* w2    = (const float*)d_in[5];
  const float* b2    = (const float*)d_in[6];
  float* out = (float*)d_out;

  const size_t MD = (size_t)Mdim * Ddim;      // 786432
  u16* xb = (u16*)d_ws;
  const size_t xb_bytes = MD * 2;             // 1.5 MB
  char* p = (char*)d_ws + xb_bytes;

  k_cvt<<<dim3((u32)(MD / 1024)), dim3(256), 0, stream>>>(x, xb);

  const size_t h_bytes    = (size_t)Edim * MD * 2;  // 157.3 MB
  const size_t t_bytes_f  = (size_t)Edim * MD * 4;  // 314.6 MB
  const size_t t_bytes_bf = (size_t)Edim * MD * 2;  // 157.3 MB

  if (ws_size >= xb_bytes + h_bytes + t_bytes_f) {
    u16* hbuf = (u16*)p;
    float* tbuf = (float*)(p + h_bytes);
    k_h<<<dim3(Edim * 48), dim3(256), 0, stream>>>(xb, w1, b1, hbuf, 0);
    k_out<1><<<dim3(Edim * 48), dim3(256), 0, stream>>>(xb, hbuf, w_lin, b_lin, w2, b2,
                                                        (void*)tbuf, out, 0);
    k_tr_f32<<<dim3((u32)(MD / 128)), dim3(256), 0, stream>>>(tbuf, out);
  } else if (ws_size >= xb_bytes + h_bytes + t_bytes_bf) {
    u16* hbuf = (u16*)p;
    u16* tbuf = (u16*)(p + h_bytes);
    k_h<<<dim3(Edim * 48), dim3(256), 0, stream>>>(xb, w1, b1, hbuf, 0);
    k_out<0><<<dim3(Edim * 48), dim3(256), 0, stream>>>(xb, hbuf, w_lin, b_lin, w2, b2,
                                                        (void*)tbuf, out, 0);
    k_tr_bf<<<dim3((u32)(MD / 256)), dim3(256), 0, stream>>>(tbuf, out);
  } else {
    // chunked fallback: per-chunk h in ws, direct strided writes (slow but correct)
    size_t avail = ws_size > xb_bytes ? ws_size - xb_bytes : 0;
    int EC = (int)(avail / (MD * 2));
    if (EC < 1) EC = 1;
    if (EC > Edim) EC = Edim;
    u16* hbuf = (u16*)p;
    for (int e0 = 0; e0 < Edim; e0 += EC) {
      int ne = (Edim - e0) < EC ? (Edim - e0) : EC;
      k_h<<<dim3(ne * 48), dim3(256), 0, stream>>>(xb, w1, b1, hbuf, e0);
      k_out<2><<<dim3(ne * 48), dim3(256), 0, stream>>>(xb, hbuf, w_lin, b_lin, w2, b2,
                                                        nullptr, out, e0);
    }
  }
}

// Round 2
// 984.088 us; speedup vs baseline: 1.0008x; 1.0008x over previous
//
#include <hip/hip_runtime.h>
#include <hip/hip_bf16.h>
#include <cstdint>

typedef __attribute__((ext_vector_type(8))) short short8;
typedef __attribute__((ext_vector_type(4))) float f32x4;
typedef unsigned short u16;
typedef unsigned int u32;

#define Mdim 1024
#define Ddim 768
#define Edim 100
#define DD (Ddim * Ddim)
#define BM 128
#define BN 128
#define BK 32

__device__ __forceinline__ u16 f2bf(float f) {
  u32 u = __builtin_bit_cast(u32, f);
  u += 0x7fffu + ((u >> 16) & 1u);   // RNE
  return (u16)(u >> 16);
}
__device__ __forceinline__ float bf2f(u16 h) {
  return __builtin_bit_cast(float, ((u32)h) << 16);
}
__device__ __forceinline__ u32 pack2(float a, float b) {
  return (u32)f2bf(a) | ((u32)f2bf(b) << 16);
}

// async global->LDS, 16B per lane; lds dest is wave-uniform base + lane*16
#define GLL16(gsrc, ldst)                                                        \
  __builtin_amdgcn_global_load_lds(                                             \
      (const __attribute__((address_space(1))) u32*)(gsrc),                     \
      (__attribute__((address_space(3))) u32*)(ldst), 16, 0, 0)

// ---------------- x: f32 -> bf16 ----------------
__global__ void k_cvt(const float* __restrict__ x, u16* __restrict__ xb) {
  size_t i = ((size_t)blockIdx.x * 256 + threadIdx.x) * 4;
  float4 v = *(const float4*)(x + i);
  uint2 r;
  r.x = pack2(v.x, v.y);
  r.y = pack2(v.z, v.w);
  *(uint2*)(xb + i) = r;
}

// ---------------- weights: f32 -> bf16, grid-stride, 8 elems/thread ----------------
__global__ __launch_bounds__(256) void k_cvtw(const float* __restrict__ w,
                                              u16* __restrict__ wb, int n8) {
  const int stride = gridDim.x * 256;
  for (int i = blockIdx.x * 256 + threadIdx.x; i < n8; i += stride) {
    const size_t o = (size_t)i * 8;
    const float4 f0 = *(const float4*)(w + o);
    const float4 f1 = *(const float4*)(w + o + 4);
    uint4 v;
    v.x = pack2(f0.x, f0.y); v.y = pack2(f0.z, f0.w);
    v.z = pack2(f1.x, f1.y); v.w = pack2(f1.z, f1.w);
    *(uint4*)(wb + o) = v;
  }
}

// ---------------- shared GEMM K-loop (m97 structure) ----------------
// A: bf16, staged via global_load_lds. B: bf16 via global_load_lds (WB16) or
// f32 reg-load + convert + ds_write (fallback). Linear LDS [128][32].
template <bool WB16>
__device__ __forceinline__ void gemm_phase(const u16* __restrict__ Ag,   // row m0 applied, stride Ddim
                                           const char* __restrict__ Wg,  // expert+n0 applied, stride Ddim
                                           u16* As, u16* Bs, f32x4 (&acc)[4][4], int t) {
  const int w = t >> 6, l = t & 63;
  const int lrow = l & 15, lk = (l >> 4) << 3;
  const int wr = ((w >> 1) << 6), wc = ((w & 1) << 6);
  for (int kt = 0; kt < Ddim; kt += BK) {
#pragma unroll
    for (int i = 0; i < 2; ++i) {
      const int r = (w << 5) + (i << 4) + (l >> 2);
      GLL16(Ag + (size_t)r * Ddim + kt + ((l & 3) << 3),
            As + (((w << 5) + (i << 4)) << 5));
    }
    if (WB16) {
#pragma unroll
      for (int i = 0; i < 2; ++i) {
        const int r = (w << 5) + (i << 4) + (l >> 2);
        GLL16((const u16*)Wg + (size_t)r * Ddim + kt + ((l & 3) << 3),
              Bs + (((w << 5) + (i << 4)) << 5));
      }
    } else {
      const int r = t >> 1, c = (t & 1) << 4;
      const float* src = (const float*)Wg + (size_t)r * Ddim + kt + c;
      const float4 f0 = *(const float4*)(src);
      const float4 f1 = *(const float4*)(src + 4);
      const float4 f2 = *(const float4*)(src + 8);
      const float4 f3 = *(const float4*)(src + 12);
      uint4 v0, v1;
      v0.x = pack2(f0.x, f0.y); v0.y = pack2(f0.z, f0.w);
      v0.z = pack2(f1.x, f1.y); v0.w = pack2(f1.z, f1.w);
      v1.x = pack2(f2.x, f2.y); v1.y = pack2(f2.z, f2.w);
      v1.z = pack2(f3.x, f3.y); v1.w = pack2(f3.z, f3.w);
      *(uint4*)(&Bs[r * 32 + c]) = v0;
      *(uint4*)(&Bs[r * 32 + c + 8]) = v1;
    }
    __syncthreads();
    short8 af[4], bfr[4];
#pragma unroll
    for (int f = 0; f < 4; ++f) {
      af[f]  = *(const short8*)(&As[(wr + f * 16 + lrow) * 32 + lk]);
      bfr[f] = *(const short8*)(&Bs[(wc + f * 16 + lrow) * 32 + lk]);
    }
#pragma unroll
    for (int fm = 0; fm < 4; ++fm)
#pragma unroll
      for (int fn = 0; fn < 4; ++fn)
        acc[fm][fn] = __builtin_amdgcn_mfma_f32_16x16x32_bf16(af[fm], bfr[fn], acc[fm][fn], 0, 0, 0);
    __syncthreads();
  }
}

// block decode: SWZ groups the 8 m-blocks of one (e, n-panel) consecutively on one XCD
template <bool SWZ>
__device__ __forceinline__ void decode_blk(int bid, int e_base, int& e, int& el,
                                           int& m0, int& n0) {
  if (SWZ) {
    const int xcd = bid & 7, j = bid >> 3;
    const int p = xcd * 75 + (j >> 3);   // panel 0..599
    el = p / 6; n0 = (p % 6) * BN; m0 = (j & 7) * BM;
    e = el;
  } else {
    el = bid / 48;
    const int r = bid % 48;
    m0 = (r / 6) * BM; n0 = (r % 6) * BN;
    e = e_base + el;
  }
}

// ---------------- kernel A: h = gelu(x @ w1^T + b1), per expert ----------------
template <bool WB16, bool SWZ>
__global__ __launch_bounds__(256) void k_h2(const u16* __restrict__ xb,
                                            const void* __restrict__ w1p,
                                            const float* __restrict__ b1,
                                            u16* __restrict__ hout, int e_base) {
  __shared__ __align__(16) u16 As[BM * BK];
  __shared__ __align__(16) u16 Bs[BN * BK];
  int e, el, m0, n0;
  decode_blk<SWZ>(blockIdx.x, e_base, e, el, m0, n0);
  const int t = threadIdx.x, l = t & 63, wv = t >> 6;
  const int wr = (wv >> 1) * 64, wc = (wv & 1) * 64, lrow = l & 15;

  f32x4 acc[4][4] = {};
  const char* Wg = WB16
      ? (const char*)((const u16*)w1p + (size_t)e * DD + (size_t)n0 * Ddim)
      : (const char*)((const float*)w1p + (size_t)e * DD + (size_t)n0 * Ddim);
  gemm_phase<WB16>(xb + (size_t)m0 * Ddim, Wg, As, Bs, acc, t);

  const float* bias = b1 + (size_t)e * Ddim + n0;
  u16* hb = hout + (size_t)el * Mdim * Ddim;
#pragma unroll
  for (int fm = 0; fm < 4; ++fm) {
    const int mb = m0 + wr + fm * 16 + ((l >> 4) << 2);
#pragma unroll
    for (int fn = 0; fn < 4; ++fn) {
      const int nc = wc + fn * 16 + lrow;
      const float bv = bias[nc];
#pragma unroll
      for (int j = 0; j < 4; ++j) {
        float v = acc[fm][fn][j] + bv;
        v = 0.5f * v * (1.0f + erff(v * 0.7071067811865475f));
        hb[(size_t)(mb + j) * Ddim + n0 + nc] = f2bf(v);
      }
    }
  }
}

// ---------------- kernel B: out_e = x @ w_lin^T + h @ w2^T + biases ----------------
// OUTMODE: 0 = bf16 ws tile [e][m][o], 1 = f32 ws tile, 2 = direct strided f32
template <bool WB16, int OUTMODE, bool SWZ>
__global__ __launch_bounds__(256) void k_out2(
    const u16* __restrict__ xb, const u16* __restrict__ hbuf,
    const void* __restrict__ wlp, const float* __restrict__ b_lin,
    const void* __restrict__ w2p, const float* __restrict__ b2,
    void* __restrict__ tout, float* __restrict__ out, int e_base) {
  __shared__ __align__(16) u16 As[BM * BK];
  __shared__ __align__(16) u16 Bs[BN * BK];
  int e, el, m0, n0;
  decode_blk<SWZ>(blockIdx.x, e_base, e, el, m0, n0);
  const int t = threadIdx.x, l = t & 63, wv = t >> 6;
  const int wr = (wv >> 1) * 64, wc = (wv & 1) * 64, lrow = l & 15;

  f32x4 acc[4][4] = {};
  {
    const char* Wg = WB16
        ? (const char*)((const u16*)wlp + (size_t)e * DD + (size_t)n0 * Ddim)
        : (const char*)((const float*)wlp + (size_t)e * DD + (size_t)n0 * Ddim);
    gemm_phase<WB16>(xb + (size_t)m0 * Ddim, Wg, As, Bs, acc, t);
  }
  {
    const u16* Ag = hbuf + (size_t)el * Mdim * Ddim + (size_t)m0 * Ddim;
    const char* Wg = WB16
        ? (const char*)((const u16*)w2p + (size_t)e * DD + (size_t)n0 * Ddim)
        : (const char*)((const float*)w2p + (size_t)e * DD + (size_t)n0 * Ddim);
    gemm_phase<WB16>(Ag, Wg, As, Bs, acc, t);
  }

  const float* bl = b_lin + (size_t)e * Ddim + n0;
  const float* bm = b2 + (size_t)e * Ddim + n0;
#pragma unroll
  for (int fm = 0; fm < 4; ++fm) {
    const int mb = m0 + wr + fm * 16 + ((l >> 4) << 2);
#pragma unroll
    for (int fn = 0; fn < 4; ++fn) {
      const int nc = wc + fn * 16 + lrow;
      const float bv = bl[nc] + bm[nc];
#pragma unroll
      for (int j = 0; j < 4; ++j) {
        float v = acc[fm][fn][j] + bv;
        if (OUTMODE == 0) {
          ((u16*)tout)[((size_t)e * Mdim + mb + j) * Ddim + n0 + nc] = f2bf(v);
        } else if (OUTMODE == 1) {
          ((float*)tout)[((size_t)e * Mdim + mb + j) * Ddim + n0 + nc] = v;
        } else {
          out[((size_t)(mb + j) * Ddim + n0 + nc) * Edim + e] = v;
        }
      }
    }
  }
}

// ---------------- transpose [E][M*D] -> [M*D][E] ----------------
__global__ __launch_bounds__(256) void k_tr_f32(const float* __restrict__ tbuf,
                                                float* __restrict__ out) {
  __shared__ __align__(16) float tile[100 * 131];  // stride 131: bank stride 3 -> conflict-free
  const int t = threadIdx.x;
  const size_t MD = (size_t)Mdim * Ddim;
  const size_t md0 = (size_t)blockIdx.x * 128;
#pragma unroll
  for (int p = 0; p < 25; ++p) {
    const int e = p * 4 + (t >> 6);
    const int c = (t & 63) * 2;
    float2 v = *(const float2*)(tbuf + (size_t)e * MD + md0 + c);
    *(float2*)(&tile[e * 131 + c]) = v;
  }
  __syncthreads();
  const size_t obase = md0 * 100;
#pragma unroll 5
  for (int i = 0; i < 50; ++i) {
    const int flat = t + i * 256;                     // < 12800
    const int mo = (int)(((u32)flat * 5243u) >> 19);  // /100
    const int e = flat - mo * 100;
    out[obase + flat] = tile[e * 131 + mo];
  }
}

__global__ __launch_bounds__(256) void k_tr_bf(const u16* __restrict__ tbuf,
                                               float* __restrict__ out) {
  __shared__ __align__(16) u16 tile[100 * 260];
  const int t = threadIdx.x;
  const size_t MD = (size_t)Mdim * Ddim;
  const size_t md0 = (size_t)blockIdx.x * 256;
#pragma unroll
  for (int p = 0; p < 25; ++p) {
    const int e = p * 4 + (t >> 6);
    const int c = (t & 63) * 4;
    uint2 v = *(const uint2*)(tbuf + (size_t)e * MD + md0 + c);
    *(uint2*)(&tile[e * 260 + c]) = v;
  }
  __syncthreads();
  const size_t obase = md0 * 100;
#pragma unroll 5
  for (int i = 0; i < 100; ++i) {
    const int flat = t + i * 256;                     // < 25600
    const int mo = (int)(((u32)flat * 5243u) >> 19);  // /100
    const int e = flat - mo * 100;
    out[obase + flat] = bf2f(tile[e * 260 + mo]);
  }
}

extern "C" void kernel_launch(void* const* d_in, const int* in_sizes, int n_in,
                              void* d_out, int out_size, void* d_ws, size_t ws_size,
                              hipStream_t stream) {
  const float* x     = (const float*)d_in[0];
  const float* w_lin = (const float*)d_in[1];
  const float* b_lin = (const float*)d_in[2];
  const float* w1    = (const float*)d_in[3];
  const float* b1    = (const float*)d_in[4];
  const float* w2    = (const float*)d_in[5];
  const float* b2    = (const float*)d_in[6];
  float* out = (float*)d_out;

  const size_t MD = (size_t)Mdim * Ddim;          // 786432
  const size_t xb_b   = MD * 2;                   // 1.57 MB
  const size_t w1_b   = (size_t)Edim * DD * 2;    // 118 MB (bf16, one matrix)
  const size_t wreg_b = 2 * w1_b;                 // 236 MB
  const size_t h_b    = (size_t)Edim * MD * 2;    // 157 MB
  const size_t tf_b   = (size_t)Edim * MD * 4;    // 315 MB
  const size_t tb_b   = h_b;
  const int NW8 = (int)((size_t)Edim * DD / 8);   // 7,372,800

  char* base = (char*)d_ws;
  u16* xb = (u16*)base;
  k_cvt<<<dim3((u32)(MD / 1024)), dim3(256), 0, stream>>>(x, xb);

  if (ws_size >= xb_b + wreg_b + h_b + tf_b) {
    // Tier A: bf16 weights + f32 tbuf (710 MB)
    u16* wreg   = (u16*)(base + xb_b);
    u16* hbuf   = (u16*)(base + xb_b + wreg_b);
    float* tbuf = (float*)(base + xb_b + wreg_b + h_b);
    k_cvtw<<<dim3(2048), dim3(256), 0, stream>>>(w1, wreg, NW8);
    k_h2<true, true><<<dim3(4800), dim3(256), 0, stream>>>(xb, wreg, b1, hbuf, 0);
    k_cvtw<<<dim3(2048), dim3(256), 0, stream>>>(w_lin, wreg, NW8);
    k_cvtw<<<dim3(2048), dim3(256), 0, stream>>>(w2, wreg + (size_t)Edim * DD, NW8);
    k_out2<true, 1, true><<<dim3(4800), dim3(256), 0, stream>>>(
        xb, hbuf, wreg, b_lin, wreg + (size_t)Edim * DD, b2, (void*)tbuf, out, 0);
    k_tr_f32<<<dim3((u32)(MD / 128)), dim3(256), 0, stream>>>(tbuf, out);
  } else if (ws_size >= xb_b + wreg_b + h_b + tb_b) {
    // Tier B: bf16 weights + bf16 tbuf (552 MB)
    u16* wreg = (u16*)(base + xb_b);
    u16* hbuf = (u16*)(base + xb_b + wreg_b);
    u16* tbuf = (u16*)(base + xb_b + wreg_b + h_b);
    k_cvtw<<<dim3(2048), dim3(256), 0, stream>>>(w1, wreg, NW8);
    k_h2<true, true><<<dim3(4800), dim3(256), 0, stream>>>(xb, wreg, b1, hbuf, 0);
    k_cvtw<<<dim3(2048), dim3(256), 0, stream>>>(w_lin, wreg, NW8);
    k_cvtw<<<dim3(2048), dim3(256), 0, stream>>>(w2, wreg + (size_t)Edim * DD, NW8);
    k_out2<true, 0, true><<<dim3(4800), dim3(256), 0, stream>>>(
        xb, hbuf, wreg, b_lin, wreg + (size_t)Edim * DD, b2, (void*)tbuf, out, 0);
    k_tr_bf<<<dim3((u32)(MD / 256)), dim3(256), 0, stream>>>(tbuf, out);
  } else if (ws_size >= xb_b + h_b + tf_b) {
    // Tier C: f32 weights (reg-staged), f32 tbuf (473 MB) — round-1-equivalent
    u16* hbuf   = (u16*)(base + xb_b);
    float* tbuf = (float*)(base + xb_b + h_b);
    k_h2<false, true><<<dim3(4800), dim3(256), 0, stream>>>(xb, w1, b1, hbuf, 0);
    k_out2<false, 1, true><<<dim3(4800), dim3(256), 0, stream>>>(
        xb, hbuf, w_lin, b_lin, w2, b2, (void*)tbuf, out, 0);
    k_tr_f32<<<dim3((u32)(MD / 128)), dim3(256), 0, stream>>>(tbuf, out);
  } else {
    // Tier D: chunked fallback, direct strided writes (slow but correct)
    size_t avail = ws_size > xb_b ? ws_size - xb_b : 0;
    int EC = (int)(avail / (MD * 2));
    if (EC < 1) EC = 1;
    if (EC > Edim) EC = Edim;
    u16* hbuf = (u16*)(base + xb_b);
    for (int e0 = 0; e0 < Edim; e0 += EC) {
      int ne = (Edim - e0) < EC ? (Edim - e0) : EC;
      k_h2<false, false><<<dim3(ne * 48), dim3(256), 0, stream>>>(xb, w1, b1, hbuf, e0);
      k_out2<false, 2, false><<<dim3(ne * 48), dim3(256), 0, stream>>>(
          xb, hbuf, w_lin, b_lin, w2, b2, nullptr, out, e0);
    }
  }
}

// Round 3
// 960.806 us; speedup vs baseline: 1.0250x; 1.0242x over previous
//
#include <hip/hip_runtime.h>
#include <hip/hip_bf16.h>
#include <cstdint>

typedef __attribute__((ext_vector_type(8))) short short8;
typedef __attribute__((ext_vector_type(4))) float f32x4;
typedef unsigned short u16;
typedef unsigned int u32;

#define Mdim 1024
#define Ddim 768
#define Edim 100
#define DD (Ddim * Ddim)
#define BM 128
#define BN 128
#define BK 32
#define TILE_E (BM * BK)   // 4096 u16 elems = 8 KB

__device__ __forceinline__ u16 f2bf(float f) {
  u32 u = __builtin_bit_cast(u32, f);
  u += 0x7fffu + ((u >> 16) & 1u);   // RNE
  return (u16)(u >> 16);
}
__device__ __forceinline__ float bf2f(u16 h) {
  return __builtin_bit_cast(float, ((u32)h) << 16);
}
__device__ __forceinline__ u32 pack2(float a, float b) {
  return (u32)f2bf(a) | ((u32)f2bf(b) << 16);
}

// async global->LDS, 16B per lane; lds dest is wave-uniform base + lane*16
#define GLL16(gsrc, ldst)                                                        \
  __builtin_amdgcn_global_load_lds(                                             \
      (const __attribute__((address_space(1))) u32*)(gsrc),                     \
      (__attribute__((address_space(3))) u32*)(ldst), 16, 0, 0)

#define WAIT_VM4 asm volatile("s_waitcnt vmcnt(4)" ::: "memory")
#define WAIT_VM0 asm volatile("s_waitcnt vmcnt(0)" ::: "memory")
#define RAW_BAR                                                                  \
  do {                                                                           \
    __builtin_amdgcn_s_barrier();                                                \
    asm volatile("" ::: "memory");                                               \
  } while (0)

// ---------------- x: f32 -> bf16 ----------------
__global__ void k_cvt(const float* __restrict__ x, u16* __restrict__ xb) {
  size_t i = ((size_t)blockIdx.x * 256 + threadIdx.x) * 4;
  float4 v = *(const float4*)(x + i);
  uint2 r;
  r.x = pack2(v.x, v.y);
  r.y = pack2(v.z, v.w);
  *(uint2*)(xb + i) = r;
}

// ---------------- weights: f32 -> bf16, grid-stride, 8 elems/thread ----------------
__global__ __launch_bounds__(256) void k_cvtw(const float* __restrict__ w,
                                              u16* __restrict__ wb, int n8) {
  const int stride = gridDim.x * 256;
  for (int i = blockIdx.x * 256 + threadIdx.x; i < n8; i += stride) {
    const size_t o = (size_t)i * 8;
    const float4 f0 = *(const float4*)(w + o);
    const float4 f1 = *(const float4*)(w + o + 4);
    uint4 v;
    v.x = pack2(f0.x, f0.y); v.y = pack2(f0.z, f0.w);
    v.z = pack2(f1.x, f1.y); v.w = pack2(f1.z, f1.w);
    *(uint4*)(wb + o) = v;
  }
}

// block decode: SWZ groups the 8 m-blocks of one (e, n-panel) consecutively on one XCD
template <bool SWZ>
__device__ __forceinline__ void decode_blk(int bid, int e_base, int& e, int& el,
                                           int& m0, int& n0) {
  if (SWZ) {
    const int xcd = bid & 7, j = bid >> 3;
    const int p = xcd * 75 + (j >> 3);   // panel 0..599
    el = p / 6; n0 = (p % 6) * BN; m0 = (j & 7) * BM;
    e = el;
  } else {
    el = bid / 48;
    const int r = bid % 48;
    m0 = (r / 6) * BM; n0 = (r % 6) * BN;
    e = e_base + el;
  }
}

// =======================================================================
// Pipelined GEMM core: depth-2 prefetch, 3 LDS buffers, counted vmcnt,
// ONE raw s_barrier per K-step. NPH=1: 24 tiles (K=768). NPH=2: 48 tiles
// (two K-phases, source switch at tile 24).
// =======================================================================
template <int NPH>
__device__ __forceinline__ void gemm_pipe(const u16* __restrict__ A0,
                                          const u16* __restrict__ A1,
                                          const u16* __restrict__ B0,
                                          const u16* __restrict__ B1,
                                          u16* As, u16* Bs,   // each [3][TILE_E]
                                          f32x4 (&acc)[4][4], int t) {
  constexpr int NT = NPH * 24;
  const int w = t >> 6, l = t & 63;
  const int lrow = l & 15, lk = (l >> 4) << 3;
  const int wr = ((w >> 1) << 6), wc = ((w & 1) << 6);
  const size_t soff = (size_t)((w << 5) + (l >> 2)) * Ddim + ((l & 3) << 3);
  const int d0 = (w << 5) << 5;   // wave's LDS elem base (w*1024)

  auto stage = [&](int bi, int tt) {
    const u16* Ab = A0; const u16* Bb = B0; int kk = tt;
    if (NPH == 2 && tt >= 24) { Ab = A1; Bb = B1; kk = tt - 24; }
    const u16* as = Ab + soff + (kk << 5);
    const u16* bs = Bb + soff + (kk << 5);
    u16* ad = As + bi * TILE_E + d0;
    u16* bd = Bs + bi * TILE_E + d0;
    GLL16(as, ad);
    GLL16(as + (size_t)16 * Ddim, ad + 512);
    GLL16(bs, bd);
    GLL16(bs + (size_t)16 * Ddim, bd + 512);
  };
  auto compute = [&](int bi) {
    const u16* ab = As + bi * TILE_E;
    const u16* bb = Bs + bi * TILE_E;
    short8 af[4], bf[4];
#pragma unroll
    for (int f = 0; f < 4; ++f) {
      af[f] = *(const short8*)(ab + (wr + f * 16 + lrow) * 32 + lk);
      bf[f] = *(const short8*)(bb + (wc + f * 16 + lrow) * 32 + lk);
    }
#pragma unroll
    for (int fm = 0; fm < 4; ++fm)
#pragma unroll
      for (int fn = 0; fn < 4; ++fn)
        acc[fm][fn] = __builtin_amdgcn_mfma_f32_16x16x32_bf16(af[fm], bf[fn], acc[fm][fn], 0, 0, 0);
  };

  // prologue: tiles 0,1 in flight; wait tile 0 (4 newest outstanding = tile 1)
  stage(0, 0);
  stage(1, 1);
  WAIT_VM4;
  RAW_BAR;

  int bi = 0;
  for (int tt = 0; tt < NT - 2; ++tt) {
    const int bi2 = bi + 2 >= 3 ? bi - 1 : bi + 2;
    stage(bi2, tt + 2);      // overwrites buffer of tile tt-1: readers done at prev barrier
    compute(bi);             // tile tt
    WAIT_VM4;                // tile tt+1 landed (tile tt+2's 4 loads may remain in flight)
    RAW_BAR;
    bi = bi + 1 >= 3 ? 0 : bi + 1;
  }
  compute(bi);               // tile NT-2
  WAIT_VM0;                  // tile NT-1 landed
  RAW_BAR;
  bi = bi + 1 >= 3 ? 0 : bi + 1;
  compute(bi);               // tile NT-1
}

// ---------------- kernel A (pipelined): h = gelu(x @ w1^T + b1) ----------------
__global__ __launch_bounds__(256, 3) void k_h3(const u16* __restrict__ xb,
                                               const u16* __restrict__ w1b,
                                               const float* __restrict__ b1,
                                               u16* __restrict__ hout) {
  __shared__ __align__(16) u16 As[3 * TILE_E];
  __shared__ __align__(16) u16 Bs[3 * TILE_E];
  int e, el, m0, n0;
  decode_blk<true>(blockIdx.x, 0, e, el, m0, n0);
  const int t = threadIdx.x, l = t & 63, wv = t >> 6;
  const int wr = (wv >> 1) * 64, wc = (wv & 1) * 64, lrow = l & 15;

  f32x4 acc[4][4] = {};
  gemm_pipe<1>(xb + (size_t)m0 * Ddim, nullptr,
               w1b + (size_t)e * DD + (size_t)n0 * Ddim, nullptr, As, Bs, acc, t);

  const float* bias = b1 + (size_t)e * Ddim + n0;
  u16* hb = hout + (size_t)el * Mdim * Ddim;
#pragma unroll
  for (int fm = 0; fm < 4; ++fm) {
    const int mb = m0 + wr + fm * 16 + ((l >> 4) << 2);
#pragma unroll
    for (int fn = 0; fn < 4; ++fn) {
      const int nc = wc + fn * 16 + lrow;
      const float bv = bias[nc];
#pragma unroll
      for (int j = 0; j < 4; ++j) {
        float v = acc[fm][fn][j] + bv;
        v = 0.5f * v * (1.0f + erff(v * 0.7071067811865475f));
        hb[(size_t)(mb + j) * Ddim + n0 + nc] = f2bf(v);
      }
    }
  }
}

// ---------------- kernel B (pipelined): x@wl^T + h@w2^T + biases -> bf16 tbuf ----------------
__global__ __launch_bounds__(256, 3) void k_out3(const u16* __restrict__ xb,
                                                 const u16* __restrict__ hbuf,
                                                 const u16* __restrict__ wlb,
                                                 const float* __restrict__ b_lin,
                                                 const u16* __restrict__ w2b,
                                                 const float* __restrict__ b2,
                                                 u16* __restrict__ tout) {
  __shared__ __align__(16) u16 As[3 * TILE_E];
  __shared__ __align__(16) u16 Bs[3 * TILE_E];
  int e, el, m0, n0;
  decode_blk<true>(blockIdx.x, 0, e, el, m0, n0);
  const int t = threadIdx.x, l = t & 63, wv = t >> 6;
  const int wr = (wv >> 1) * 64, wc = (wv & 1) * 64, lrow = l & 15;

  f32x4 acc[4][4] = {};
  gemm_pipe<2>(xb + (size_t)m0 * Ddim,
               hbuf + (size_t)el * Mdim * Ddim + (size_t)m0 * Ddim,
               wlb + (size_t)e * DD + (size_t)n0 * Ddim,
               w2b + (size_t)e * DD + (size_t)n0 * Ddim, As, Bs, acc, t);

  const float* bl = b_lin + (size_t)e * Ddim + n0;
  const float* bm = b2 + (size_t)e * Ddim + n0;
#pragma unroll
  for (int fm = 0; fm < 4; ++fm) {
    const int mb = m0 + wr + fm * 16 + ((l >> 4) << 2);
#pragma unroll
    for (int fn = 0; fn < 4; ++fn) {
      const int nc = wc + fn * 16 + lrow;
      const float bv = bl[nc] + bm[nc];
#pragma unroll
      for (int j = 0; j < 4; ++j) {
        float v = acc[fm][fn][j] + bv;
        tout[((size_t)e * Mdim + mb + j) * Ddim + n0 + nc] = f2bf(v);
      }
    }
  }
}

// =======================================================================
// Legacy (non-pipelined) path, kept for low-workspace fallback tiers.
// =======================================================================
__device__ __forceinline__ void gemm_phase_f32(const u16* __restrict__ Ag,
                                               const float* __restrict__ Wg,
                                               u16* As, u16* Bs, f32x4 (&acc)[4][4], int t) {
  const int w = t >> 6, l = t & 63;
  const int lrow = l & 15, lk = (l >> 4) << 3;
  const int wr = ((w >> 1) << 6), wc = ((w & 1) << 6);
  for (int kt = 0; kt < Ddim; kt += BK) {
#pragma unroll
    for (int i = 0; i < 2; ++i) {
      GLL16(Ag + (size_t)((w << 5) + (i << 4) + (l >> 2)) * Ddim + kt + ((l & 3) << 3),
            As + (((w << 5) + (i << 4)) << 5));
    }
    {
      const int r = t >> 1, c = (t & 1) << 4;
      const float* src = Wg + (size_t)r * Ddim + kt + c;
      const float4 f0 = *(const float4*)(src);
      const float4 f1 = *(const float4*)(src + 4);
      const float4 f2 = *(const float4*)(src + 8);
      const float4 f3 = *(const float4*)(src + 12);
      uint4 v0, v1;
      v0.x = pack2(f0.x, f0.y); v0.y = pack2(f0.z, f0.w);
      v0.z = pack2(f1.x, f1.y); v0.w = pack2(f1.z, f1.w);
      v1.x = pack2(f2.x, f2.y); v1.y = pack2(f2.z, f2.w);
      v1.z = pack2(f3.x, f3.y); v1.w = pack2(f3.z, f3.w);
      *(uint4*)(&Bs[r * 32 + c]) = v0;
      *(uint4*)(&Bs[r * 32 + c + 8]) = v1;
    }
    __syncthreads();
    short8 af[4], bfr[4];
#pragma unroll
    for (int f = 0; f < 4; ++f) {
      af[f]  = *(const short8*)(&As[(wr + f * 16 + lrow) * 32 + lk]);
      bfr[f] = *(const short8*)(&Bs[(wc + f * 16 + lrow) * 32 + lk]);
    }
#pragma unroll
    for (int fm = 0; fm < 4; ++fm)
#pragma unroll
      for (int fn = 0; fn < 4; ++fn)
        acc[fm][fn] = __builtin_amdgcn_mfma_f32_16x16x32_bf16(af[fm], bfr[fn], acc[fm][fn], 0, 0, 0);
    __syncthreads();
  }
}

template <bool SWZ>
__global__ __launch_bounds__(256) void k_h2(const u16* __restrict__ xb,
                                            const float* __restrict__ w1,
                                            const float* __restrict__ b1,
                                            u16* __restrict__ hout, int e_base) {
  __shared__ __align__(16) u16 As[BM * BK];
  __shared__ __align__(16) u16 Bs[BN * BK];
  int e, el, m0, n0;
  decode_blk<SWZ>(blockIdx.x, e_base, e, el, m0, n0);
  const int t = threadIdx.x, l = t & 63, wv = t >> 6;
  const int wr = (wv >> 1) * 64, wc = (wv & 1) * 64, lrow = l & 15;
  f32x4 acc[4][4] = {};
  gemm_phase_f32(xb + (size_t)m0 * Ddim, w1 + (size_t)e * DD + (size_t)n0 * Ddim, As, Bs, acc, t);
  const float* bias = b1 + (size_t)e * Ddim + n0;
  u16* hb = hout + (size_t)el * Mdim * Ddim;
#pragma unroll
  for (int fm = 0; fm < 4; ++fm) {
    const int mb = m0 + wr + fm * 16 + ((l >> 4) << 2);
#pragma unroll
    for (int fn = 0; fn < 4; ++fn) {
      const int nc = wc + fn * 16 + lrow;
      const float bv = bias[nc];
#pragma unroll
      for (int j = 0; j < 4; ++j) {
        float v = acc[fm][fn][j] + bv;
        v = 0.5f * v * (1.0f + erff(v * 0.7071067811865475f));
        hb[(size_t)(mb + j) * Ddim + n0 + nc] = f2bf(v);
      }
    }
  }
}

template <int OUTMODE, bool SWZ>  // 1 = f32 ws tile, 2 = direct strided f32
__global__ __launch_bounds__(256) void k_out2(
    const u16* __restrict__ xb, const u16* __restrict__ hbuf,
    const float* __restrict__ wl, const float* __restrict__ b_lin,
    const float* __restrict__ w2, const float* __restrict__ b2,
    void* __restrict__ tout, float* __restrict__ out, int e_base) {
  __shared__ __align__(16) u16 As[BM * BK];
  __shared__ __align__(16) u16 Bs[BN * BK];
  int e, el, m0, n0;
  decode_blk<SWZ>(blockIdx.x, e_base, e, el, m0, n0);
  const int t = threadIdx.x, l = t & 63, wv = t >> 6;
  const int wr = (wv >> 1) * 64, wc = (wv & 1) * 64, lrow = l & 15;
  f32x4 acc[4][4] = {};
  gemm_phase_f32(xb + (size_t)m0 * Ddim, wl + (size_t)e * DD + (size_t)n0 * Ddim, As, Bs, acc, t);
  gemm_phase_f32(hbuf + (size_t)el * Mdim * Ddim + (size_t)m0 * Ddim,
                 w2 + (size_t)e * DD + (size_t)n0 * Ddim, As, Bs, acc, t);
  const float* bl = b_lin + (size_t)e * Ddim + n0;
  const float* bm = b2 + (size_t)e * Ddim + n0;
#pragma unroll
  for (int fm = 0; fm < 4; ++fm) {
    const int mb = m0 + wr + fm * 16 + ((l >> 4) << 2);
#pragma unroll
    for (int fn = 0; fn < 4; ++fn) {
      const int nc = wc + fn * 16 + lrow;
      const float bv = bl[nc] + bm[nc];
#pragma unroll
      for (int j = 0; j < 4; ++j) {
        float v = acc[fm][fn][j] + bv;
        if (OUTMODE == 1) {
          ((float*)tout)[((size_t)e * Mdim + mb + j) * Ddim + n0 + nc] = v;
        } else {
          out[((size_t)(mb + j) * Ddim + n0 + nc) * Edim + e] = v;
        }
      }
    }
  }
}

// ---------------- transpose [E][M*D] -> [M*D][E] ----------------
__global__ __launch_bounds__(256) void k_tr_f32(const float* __restrict__ tbuf,
                                                float* __restrict__ out) {
  __shared__ __align__(16) float tile[100 * 131];
  const int t = threadIdx.x;
  const size_t MD = (size_t)Mdim * Ddim;
  const size_t md0 = (size_t)blockIdx.x * 128;
#pragma unroll
  for (int p = 0; p < 25; ++p) {
    const int e = p * 4 + (t >> 6);
    const int c = (t & 63) * 2;
    float2 v = *(const float2*)(tbuf + (size_t)e * MD + md0 + c);
    *(float2*)(&tile[e * 131 + c]) = v;
  }
  __syncthreads();
  const size_t obase = md0 * 100;
#pragma unroll 5
  for (int i = 0; i < 50; ++i) {
    const int flat = t + i * 256;
    const int mo = (int)(((u32)flat * 5243u) >> 19);
    const int e = flat - mo * 100;
    out[obase + flat] = tile[e * 131 + mo];
  }
}

__global__ __launch_bounds__(256) void k_tr_bf(const u16* __restrict__ tbuf,
                                               float* __restrict__ out) {
  __shared__ __align__(16) u16 tile[100 * 260];
  const int t = threadIdx.x;
  const size_t MD = (size_t)Mdim * Ddim;
  const size_t md0 = (size_t)blockIdx.x * 256;
#pragma unroll
  for (int p = 0; p < 25; ++p) {
    const int e = p * 4 + (t >> 6);
    const int c = (t & 63) * 4;
    uint2 v = *(const uint2*)(tbuf + (size_t)e * MD + md0 + c);
    *(uint2*)(&tile[e * 260 + c]) = v;
  }
  __syncthreads();
  const size_t obase = md0 * 100;
#pragma unroll 5
  for (int i = 0; i < 100; ++i) {
    const int flat = t + i * 256;
    const int mo = (int)(((u32)flat * 5243u) >> 19);
    const int e = flat - mo * 100;
    out[obase + flat] = bf2f(tile[e * 260 + mo]);
  }
}

extern "C" void kernel_launch(void* const* d_in, const int* in_sizes, int n_in,
                              void* d_out, int out_size, void* d_ws, size_t ws_size,
                              hipStream_t stream) {
  const float* x     = (const float*)d_in[0];
  const float* w_lin = (const float*)d_in[1];
  const float* b_lin = (const float*)d_in[2];
  const float* w1    = (const float*)d_in[3];
  const float* b1    = (const float*)d_in[4];
  const float* w2    = (const float*)d_in[5];
  const float* b2    = (const float*)d_in[6];
  float* out = (float*)d_out;

  const size_t MD = (size_t)Mdim * Ddim;          // 786432
  const size_t xb_b   = MD * 2;                   // 1.57 MB
  const size_t w1_b   = (size_t)Edim * DD * 2;    // 118 MB
  const size_t wreg_b = 2 * w1_b;                 // 236 MB
  const size_t h_b    = (size_t)Edim * MD * 2;    // 157 MB
  const size_t tf_b   = (size_t)Edim * MD * 4;    // 315 MB
  const size_t tb_b   = h_b;                      // 157 MB
  const int NW8 = (int)((size_t)Edim * DD / 8);   // 7,372,800

  char* base = (char*)d_ws;
  u16* xb = (u16*)base;
  k_cvt<<<dim3((u32)(MD / 1024)), dim3(256), 0, stream>>>(x, xb);

  if (ws_size >= xb_b + wreg_b + h_b + tb_b) {
    // Preferred: pipelined bf16 GEMMs + bf16 tbuf (552 MB)
    u16* wreg = (u16*)(base + xb_b);
    u16* hbuf = (u16*)(base + xb_b + wreg_b);
    u16* tbuf = (u16*)(base + xb_b + wreg_b + h_b);
    k_cvtw<<<dim3(2048), dim3(256), 0, stream>>>(w1, wreg, NW8);
    k_h3<<<dim3(4800), dim3(256), 0, stream>>>(xb, wreg, b1, hbuf);
    k_cvtw<<<dim3(2048), dim3(256), 0, stream>>>(w_lin, wreg, NW8);
    k_cvtw<<<dim3(2048), dim3(256), 0, stream>>>(w2, wreg + (size_t)Edim * DD, NW8);
    k_out3<<<dim3(4800), dim3(256), 0, stream>>>(xb, hbuf, wreg, b_lin,
                                                 wreg + (size_t)Edim * DD, b2, tbuf);
    k_tr_bf<<<dim3((u32)(MD / 256)), dim3(256), 0, stream>>>(tbuf, out);
  } else if (ws_size >= xb_b + h_b + tf_b) {
    // Fallback: f32 weights reg-staged, f32 tbuf (473 MB)
    u16* hbuf   = (u16*)(base + xb_b);
    float* tbuf = (float*)(base + xb_b + h_b);
    k_h2<true><<<dim3(4800), dim3(256), 0, stream>>>(xb, w1, b1, hbuf, 0);
    k_out2<1, true><<<dim3(4800), dim3(256), 0, stream>>>(xb, hbuf, w_lin, b_lin, w2, b2,
                                                          (void*)tbuf, out, 0);
    k_tr_f32<<<dim3((u32)(MD / 128)), dim3(256), 0, stream>>>(tbuf, out);
  } else {
    // Chunked fallback: direct strided writes (slow but correct)
    size_t avail = ws_size > xb_b ? ws_size - xb_b : 0;
    int EC = (int)(avail / (MD * 2));
    if (EC < 1) EC = 1;
    if (EC > Edim) EC = Edim;
    u16* hbuf = (u16*)(base + xb_b);
    for (int e0 = 0; e0 < Edim; e0 += EC) {
      int ne = (Edim - e0) < EC ? (Edim - e0) : EC;
      k_h2<false><<<dim3(ne * 48), dim3(256), 0, stream>>>(xb, w1, b1, hbuf, e0);
      k_out2<2, false><<<dim3(ne * 48), dim3(256), 0, stream>>>(
          xb, hbuf, w_lin, b_lin, w2, b2, nullptr, out, e0);
    }
  }
}

// Round 4
// 907.379 us; speedup vs baseline: 1.0854x; 1.0589x over previous
//
#include <hip/hip_runtime.h>
#include <hip/hip_bf16.h>
#include <cstdint>

typedef __attribute__((ext_vector_type(8))) short short8;
typedef __attribute__((ext_vector_type(4))) float f32x4;
typedef unsigned short u16;
typedef unsigned int u32;

#define Mdim 1024
#define Ddim 768
#define Edim 100
#define DD (Ddim * Ddim)
#define BM 128
#define BN 256
#define BK 32
#define TILE_A (BM * BK)   // 4096 elems = 8 KB
#define TILE_B (BN * BK)   // 8192 elems = 16 KB

__device__ __forceinline__ u16 f2bf(float f) {
  u32 u = __builtin_bit_cast(u32, f);
  u += 0x7fffu + ((u >> 16) & 1u);   // RNE
  return (u16)(u >> 16);
}
__device__ __forceinline__ float bf2f(u16 h) {
  return __builtin_bit_cast(float, ((u32)h) << 16);
}
__device__ __forceinline__ u32 pack2(float a, float b) {
  return (u32)f2bf(a) | ((u32)f2bf(b) << 16);
}

// async global->LDS, 16B per lane; lds dest is wave-uniform base + lane*16
#define GLL16(gsrc, ldst)                                                        \
  __builtin_amdgcn_global_load_lds(                                             \
      (const __attribute__((address_space(1))) u32*)(gsrc),                     \
      (__attribute__((address_space(3))) u32*)(ldst), 16, 0, 0)

#define WAIT_VM6 asm volatile("s_waitcnt vmcnt(6)" ::: "memory")
#define WAIT_VM0 asm volatile("s_waitcnt vmcnt(0)" ::: "memory")
#define RAW_BAR                                                                  \
  do {                                                                           \
    __builtin_amdgcn_s_barrier();                                                \
    asm volatile("" ::: "memory");                                               \
  } while (0)

// ---------------- x: f32 -> bf16 ----------------
__global__ void k_cvt(const float* __restrict__ x, u16* __restrict__ xb) {
  size_t i = ((size_t)blockIdx.x * 256 + threadIdx.x) * 4;
  float4 v = *(const float4*)(x + i);
  uint2 r;
  r.x = pack2(v.x, v.y);
  r.y = pack2(v.z, v.w);
  *(uint2*)(xb + i) = r;
}

// ---------------- weights: f32 -> bf16, grid-stride ----------------
__global__ __launch_bounds__(256) void k_cvtw(const float* __restrict__ w,
                                              u16* __restrict__ wb, int n8) {
  const int stride = gridDim.x * 256;
  for (int i = blockIdx.x * 256 + threadIdx.x; i < n8; i += stride) {
    const size_t o = (size_t)i * 8;
    const float4 f0 = *(const float4*)(w + o);
    const float4 f1 = *(const float4*)(w + o + 4);
    uint4 v;
    v.x = pack2(f0.x, f0.y); v.y = pack2(f0.z, f0.w);
    v.z = pack2(f1.x, f1.y); v.w = pack2(f1.z, f1.w);
    *(uint4*)(wb + o) = v;
  }
}

// panel-contiguous XCD decode: 2400 blocks = 300 panels x 8 m-blocks.
// bids with equal bid%8 share an XCD; s enumerates (panel, m) so a panel's
// 8 m-blocks (and an expert's 24 blocks) stay on one XCD.
__device__ __forceinline__ void decode2(int bid, int& el, int& m0, int& n0) {
  const int s = (bid & 7) * 300 + (bid >> 3);   // 0..2399
  const int p = s >> 3;                          // panel 0..299
  el = p / 3;
  const int np = p - el * 3;
  m0 = (s & 7) * BM;
  n0 = np * BN;
}

// =======================================================================
// Pipelined GEMM core v2: block 128x256, 4 waves, wave tile 64x128.
// Depth-2 prefetch, 3 LDS buffers, counted vmcnt(6), 1 barrier/K-step.
// LDS bank-conflict-free via both-sides XOR swizzle:
//   store:  LDS[r][s'] = global[r][s' ^ ((r>>1)&3)]  (via pre-swizzled src col)
//   read :  slot' = k16 ^ ((lrow>>1)&3)              (per-thread constant)
// =======================================================================
template <int NPH>
__device__ __forceinline__ void gemm_pipe2(const u16* __restrict__ A0,
                                           const u16* __restrict__ A1,
                                           const u16* __restrict__ B0,
                                           const u16* __restrict__ B1,
                                           u16* As, u16* Bs,   // [3][TILE_A], [3][TILE_B]
                                           f32x4 (&acc)[4][8], int t) {
  constexpr int NT = NPH * 24;
  const int w = t >> 6, l = t & 63;
  const int lrow = l & 15;
  const int lane_off = lrow * 32 + (((l >> 4) ^ ((lrow >> 1) & 3)) << 3);  // elems
  const int wr = (w >> 1) << 6;    // 0 / 64
  const int wc = (w & 1) << 7;     // 0 / 128
  // staging source: per-lane row (l>>2), pre-swizzled col
  const size_t sA = (size_t)(l >> 2) * Ddim + (((l & 3) ^ ((l >> 3) & 3)) << 3);

  auto stage = [&](int bi, int tt) {
    const u16* Ab = A0; const u16* Bb = B0; int kk = tt;
    if (NPH == 2 && tt >= 24) { Ab = A1; Bb = B1; kk = tt - 24; }
    const u16* as = Ab + sA + (kk << 5) + (size_t)(w << 5) * Ddim;
    const u16* bs = Bb + sA + (kk << 5) + (size_t)(w << 6) * Ddim;
    u16* ad = As + bi * TILE_A + (w << 10);
    u16* bd = Bs + bi * TILE_B + (w << 11);
    GLL16(as, ad);
    GLL16(as + (size_t)16 * Ddim, ad + 512);
    GLL16(bs, bd);
    GLL16(bs + (size_t)16 * Ddim, bd + 512);
    GLL16(bs + (size_t)32 * Ddim, bd + 1024);
    GLL16(bs + (size_t)48 * Ddim, bd + 1536);
  };
  auto compute = [&](int bi) {
    const u16* ab = As + bi * TILE_A + wr * 32 + lane_off;
    const u16* bb = Bs + bi * TILE_B + wc * 32 + lane_off;
    short8 af[4], bf[8];
#pragma unroll
    for (int f = 0; f < 4; ++f) af[f] = *(const short8*)(ab + f * 512);
#pragma unroll
    for (int f = 0; f < 8; ++f) bf[f] = *(const short8*)(bb + f * 512);
#pragma unroll
    for (int fm = 0; fm < 4; ++fm)
#pragma unroll
      for (int fn = 0; fn < 8; ++fn)
        acc[fm][fn] = __builtin_amdgcn_mfma_f32_16x16x32_bf16(af[fm], bf[fn], acc[fm][fn], 0, 0, 0);
  };

  stage(0, 0);
  stage(1, 1);
  WAIT_VM6;            // tile 0 landed (6 newest = tile 1 may be in flight)
  RAW_BAR;

  int bi = 0;
  for (int tt = 0; tt < NT - 2; ++tt) {
    const int bi2 = bi + 2 >= 3 ? bi - 1 : bi + 2;
    stage(bi2, tt + 2);   // overwrites tile tt-1's buffer: readers done at prev barrier
    compute(bi);          // tile tt
    WAIT_VM6;             // tile tt+1 landed
    RAW_BAR;
    bi = bi + 1 >= 3 ? 0 : bi + 1;
  }
  compute(bi);            // tile NT-2
  WAIT_VM0;               // tile NT-1 landed
  RAW_BAR;
  bi = bi + 1 >= 3 ? 0 : bi + 1;
  compute(bi);            // tile NT-1
}

// ---------------- kernel A: h = gelu(x @ w1^T + b1) ----------------
__global__ __launch_bounds__(256, 2) void k_h4(const u16* __restrict__ xb,
                                               const u16* __restrict__ w1b,
                                               const float* __restrict__ b1,
                                               u16* __restrict__ hout) {
  __shared__ __align__(16) u16 As[3 * TILE_A];
  __shared__ __align__(16) u16 Bs[3 * TILE_B];
  int el, m0, n0;
  decode2(blockIdx.x, el, m0, n0);
  const int t = threadIdx.x, l = t & 63, wv = t >> 6;
  const int wr = (wv >> 1) * 64, wc = (wv & 1) * 128, lrow = l & 15;

  f32x4 acc[4][8] = {};
  gemm_pipe2<1>(xb + (size_t)m0 * Ddim, nullptr,
                w1b + (size_t)el * DD + (size_t)n0 * Ddim, nullptr, As, Bs, acc, t);

  const float* bias = b1 + (size_t)el * Ddim + n0;
  u16* hb = hout + (size_t)el * Mdim * Ddim;
#pragma unroll
  for (int fm = 0; fm < 4; ++fm) {
    const int mb = m0 + wr + fm * 16 + ((l >> 4) << 2);
#pragma unroll
    for (int fn = 0; fn < 8; ++fn) {
      const int nc = wc + fn * 16 + lrow;
      const float bv = bias[nc];
#pragma unroll
      for (int j = 0; j < 4; ++j) {
        float v = acc[fm][fn][j] + bv;
        v = 0.5f * v * (1.0f + erff(v * 0.7071067811865475f));
        hb[(size_t)(mb + j) * Ddim + n0 + nc] = f2bf(v);
      }
    }
  }
}

// ---------------- kernel B: x@wl^T + h@w2^T + biases -> bf16 tbuf ----------------
__global__ __launch_bounds__(256, 2) void k_out4(const u16* __restrict__ xb,
                                                 const u16* __restrict__ hbuf,
                                                 const u16* __restrict__ wlb,
                                                 const float* __restrict__ b_lin,
                                                 const u16* __restrict__ w2b,
                                                 const float* __restrict__ b2,
                                                 u16* __restrict__ tout) {
  __shared__ __align__(16) u16 As[3 * TILE_A];
  __shared__ __align__(16) u16 Bs[3 * TILE_B];
  int el, m0, n0;
  decode2(blockIdx.x, el, m0, n0);
  const int t = threadIdx.x, l = t & 63, wv = t >> 6;
  const int wr = (wv >> 1) * 64, wc = (wv & 1) * 128, lrow = l & 15;

  f32x4 acc[4][8] = {};
  gemm_pipe2<2>(xb + (size_t)m0 * Ddim,
                hbuf + (size_t)el * Mdim * Ddim + (size_t)m0 * Ddim,
                wlb + (size_t)el * DD + (size_t)n0 * Ddim,
                w2b + (size_t)el * DD + (size_t)n0 * Ddim, As, Bs, acc, t);

  const float* bl = b_lin + (size_t)el * Ddim + n0;
  const float* bm = b2 + (size_t)el * Ddim + n0;
#pragma unroll
  for (int fm = 0; fm < 4; ++fm) {
    const int mb = m0 + wr + fm * 16 + ((l >> 4) << 2);
#pragma unroll
    for (int fn = 0; fn < 8; ++fn) {
      const int nc = wc + fn * 16 + lrow;
      const float bv = bl[nc] + bm[nc];
#pragma unroll
      for (int j = 0; j < 4; ++j) {
        float v = acc[fm][fn][j] + bv;
        tout[((size_t)el * Mdim + mb + j) * Ddim + n0 + nc] = f2bf(v);
      }
    }
  }
}

// =======================================================================
// Legacy (non-pipelined) path for low-workspace fallback tiers.
// =======================================================================
__device__ __forceinline__ void gemm_phase_f32(const u16* __restrict__ Ag,
                                               const float* __restrict__ Wg,
                                               u16* As, u16* Bs, f32x4 (&acc)[4][4], int t) {
  const int w = t >> 6, l = t & 63;
  const int lrow = l & 15, lk = (l >> 4) << 3;
  const int wr = ((w >> 1) << 6), wc = ((w & 1) << 6);
  for (int kt = 0; kt < Ddim; kt += BK) {
#pragma unroll
    for (int i = 0; i < 2; ++i) {
      GLL16(Ag + (size_t)((w << 5) + (i << 4) + (l >> 2)) * Ddim + kt + ((l & 3) << 3),
            As + (((w << 5) + (i << 4)) << 5));
    }
    {
      const int r = t >> 1, c = (t & 1) << 4;
      const float* src = Wg + (size_t)r * Ddim + kt + c;
      const float4 f0 = *(const float4*)(src);
      const float4 f1 = *(const float4*)(src + 4);
      const float4 f2 = *(const float4*)(src + 8);
      const float4 f3 = *(const float4*)(src + 12);
      uint4 v0, v1;
      v0.x = pack2(f0.x, f0.y); v0.y = pack2(f0.z, f0.w);
      v0.z = pack2(f1.x, f1.y); v0.w = pack2(f1.z, f1.w);
      v1.x = pack2(f2.x, f2.y); v1.y = pack2(f2.z, f2.w);
      v1.z = pack2(f3.x, f3.y); v1.w = pack2(f3.z, f3.w);
      *(uint4*)(&Bs[r * 32 + c]) = v0;
      *(uint4*)(&Bs[r * 32 + c + 8]) = v1;
    }
    __syncthreads();
    short8 af[4], bfr[4];
#pragma unroll
    for (int f = 0; f < 4; ++f) {
      af[f]  = *(const short8*)(&As[(wr + f * 16 + lrow) * 32 + lk]);
      bfr[f] = *(const short8*)(&Bs[(wc + f * 16 + lrow) * 32 + lk]);
    }
#pragma unroll
    for (int fm = 0; fm < 4; ++fm)
#pragma unroll
      for (int fn = 0; fn < 4; ++fn)
        acc[fm][fn] = __builtin_amdgcn_mfma_f32_16x16x32_bf16(af[fm], bfr[fn], acc[fm][fn], 0, 0, 0);
    __syncthreads();
  }
}

template <bool SWZ>
__device__ __forceinline__ void decode_blk(int bid, int e_base, int& e, int& el,
                                           int& m0, int& n0) {
  if (SWZ) {
    const int xcd = bid & 7, j = bid >> 3;
    const int p = xcd * 75 + (j >> 3);
    el = p / 6; n0 = (p % 6) * 128; m0 = (j & 7) * 128;
    e = el;
  } else {
    el = bid / 48;
    const int r = bid % 48;
    m0 = (r / 6) * 128; n0 = (r % 6) * 128;
    e = e_base + el;
  }
}

template <bool SWZ>
__global__ __launch_bounds__(256) void k_h2(const u16* __restrict__ xb,
                                            const float* __restrict__ w1,
                                            const float* __restrict__ b1,
                                            u16* __restrict__ hout, int e_base) {
  __shared__ __align__(16) u16 As[128 * BK];
  __shared__ __align__(16) u16 Bs[128 * BK];
  int e, el, m0, n0;
  decode_blk<SWZ>(blockIdx.x, e_base, e, el, m0, n0);
  const int t = threadIdx.x, l = t & 63, wv = t >> 6;
  const int wr = (wv >> 1) * 64, wc = (wv & 1) * 64, lrow = l & 15;
  f32x4 acc[4][4] = {};
  gemm_phase_f32(xb + (size_t)m0 * Ddim, w1 + (size_t)e * DD + (size_t)n0 * Ddim, As, Bs, acc, t);
  const float* bias = b1 + (size_t)e * Ddim + n0;
  u16* hb = hout + (size_t)el * Mdim * Ddim;
#pragma unroll
  for (int fm = 0; fm < 4; ++fm) {
    const int mb = m0 + wr + fm * 16 + ((l >> 4) << 2);
#pragma unroll
    for (int fn = 0; fn < 4; ++fn) {
      const int nc = wc + fn * 16 + lrow;
      const float bv = bias[nc];
#pragma unroll
      for (int j = 0; j < 4; ++j) {
        float v = acc[fm][fn][j] + bv;
        v = 0.5f * v * (1.0f + erff(v * 0.7071067811865475f));
        hb[(size_t)(mb + j) * Ddim + n0 + nc] = f2bf(v);
      }
    }
  }
}

template <int OUTMODE, bool SWZ>  // 1 = f32 ws tile, 2 = direct strided f32
__global__ __launch_bounds__(256) void k_out2(
    const u16* __restrict__ xb, const u16* __restrict__ hbuf,
    const float* __restrict__ wl, const float* __restrict__ b_lin,
    const float* __restrict__ w2, const float* __restrict__ b2,
    void* __restrict__ tout, float* __restrict__ out, int e_base) {
  __shared__ __align__(16) u16 As[128 * BK];
  __shared__ __align__(16) u16 Bs[128 * BK];
  int e, el, m0, n0;
  decode_blk<SWZ>(blockIdx.x, e_base, e, el, m0, n0);
  const int t = threadIdx.x, l = t & 63, wv = t >> 6;
  const int wr = (wv >> 1) * 64, wc = (wv & 1) * 64, lrow = l & 15;
  f32x4 acc[4][4] = {};
  gemm_phase_f32(xb + (size_t)m0 * Ddim, wl + (size_t)e * DD + (size_t)n0 * Ddim, As, Bs, acc, t);
  gemm_phase_f32(hbuf + (size_t)el * Mdim * Ddim + (size_t)m0 * Ddim,
                 w2 + (size_t)e * DD + (size_t)n0 * Ddim, As, Bs, acc, t);
  const float* bl = b_lin + (size_t)e * Ddim + n0;
  const float* bm = b2 + (size_t)e * Ddim + n0;
#pragma unroll
  for (int fm = 0; fm < 4; ++fm) {
    const int mb = m0 + wr + fm * 16 + ((l >> 4) << 2);
#pragma unroll
    for (int fn = 0; fn < 4; ++fn) {
      const int nc = wc + fn * 16 + lrow;
      const float bv = bl[nc] + bm[nc];
#pragma unroll
      for (int j = 0; j < 4; ++j) {
        float v = acc[fm][fn][j] + bv;
        if (OUTMODE == 1) {
          ((float*)tout)[((size_t)e * Mdim + mb + j) * Ddim + n0 + nc] = v;
        } else {
          out[((size_t)(mb + j) * Ddim + n0 + nc) * Edim + e] = v;
        }
      }
    }
  }
}

// ---------------- transpose [E][M*D] -> [M*D][E] ----------------
__global__ __launch_bounds__(256) void k_tr_f32(const float* __restrict__ tbuf,
                                                float* __restrict__ out) {
  __shared__ __align__(16) float tile[100 * 131];
  const int t = threadIdx.x;
  const size_t MD = (size_t)Mdim * Ddim;
  const size_t md0 = (size_t)blockIdx.x * 128;
#pragma unroll
  for (int p = 0; p < 25; ++p) {
    const int e = p * 4 + (t >> 6);
    const int c = (t & 63) * 2;
    float2 v = *(const float2*)(tbuf + (size_t)e * MD + md0 + c);
    *(float2*)(&tile[e * 131 + c]) = v;
  }
  __syncthreads();
  const size_t obase = md0 * 100;
#pragma unroll 5
  for (int i = 0; i < 50; ++i) {
    const int flat = t + i * 256;
    const int mo = (int)(((u32)flat * 5243u) >> 19);
    const int e = flat - mo * 100;
    out[obase + flat] = tile[e * 131 + mo];
  }
}

__global__ __launch_bounds__(256) void k_tr_bf(const u16* __restrict__ tbuf,
                                               float* __restrict__ out) {
  __shared__ __align__(16) u16 tile[100 * 260];
  const int t = threadIdx.x;
  const size_t MD = (size_t)Mdim * Ddim;
  const size_t md0 = (size_t)blockIdx.x * 256;
#pragma unroll
  for (int p = 0; p < 25; ++p) {
    const int e = p * 4 + (t >> 6);
    const int c = (t & 63) * 4;
    uint2 v = *(const uint2*)(tbuf + (size_t)e * MD + md0 + c);
    *(uint2*)(&tile[e * 260 + c]) = v;
  }
  __syncthreads();
  const size_t obase = md0 * 100;
#pragma unroll 5
  for (int i = 0; i < 100; ++i) {
    const int flat = t + i * 256;
    const int mo = (int)(((u32)flat * 5243u) >> 19);
    const int e = flat - mo * 100;
    out[obase + flat] = bf2f(tile[e * 260 + mo]);
  }
}

extern "C" void kernel_launch(void* const* d_in, const int* in_sizes, int n_in,
                              void* d_out, int out_size, void* d_ws, size_t ws_size,
                              hipStream_t stream) {
  const float* x     = (const float*)d_in[0];
  const float* w_lin = (const float*)d_in[1];
  const float* b_lin = (const float*)d_in[2];
  const float* w1    = (const float*)d_in[3];
  const float* b1    = (const float*)d_in[4];
  const float* w2    = (const float*)d_in[5];
  const float* b2    = (const float*)d_in[6];
  float* out = (float*)d_out;

  const size_t MD = (size_t)Mdim * Ddim;          // 786432
  const size_t xb_b   = MD * 2;                   // 1.57 MB
  const size_t w1_b   = (size_t)Edim * DD * 2;    // 118 MB
  const size_t wreg_b = 2 * w1_b;                 // 236 MB
  const size_t h_b    = (size_t)Edim * MD * 2;    // 157 MB
  const size_t tf_b   = (size_t)Edim * MD * 4;    // 315 MB
  const size_t tb_b   = h_b;                      // 157 MB
  const int NW8 = (int)((size_t)Edim * DD / 8);   // 7,372,800

  char* base = (char*)d_ws;
  u16* xb = (u16*)base;
  k_cvt<<<dim3((u32)(MD / 1024)), dim3(256), 0, stream>>>(x, xb);

  if (ws_size >= xb_b + wreg_b + h_b + tb_b) {
    // Preferred: pipelined bf16 GEMMs (128x256 tile, swizzled LDS) + bf16 tbuf
    u16* wreg = (u16*)(base + xb_b);
    u16* hbuf = (u16*)(base + xb_b + wreg_b);
    u16* tbuf = (u16*)(base + xb_b + wreg_b + h_b);
    k_cvtw<<<dim3(2048), dim3(256), 0, stream>>>(w1, wreg, NW8);
    k_h4<<<dim3(2400), dim3(256), 0, stream>>>(xb, wreg, b1, hbuf);
    k_cvtw<<<dim3(2048), dim3(256), 0, stream>>>(w_lin, wreg, NW8);
    k_cvtw<<<dim3(2048), dim3(256), 0, stream>>>(w2, wreg + (size_t)Edim * DD, NW8);
    k_out4<<<dim3(2400), dim3(256), 0, stream>>>(xb, hbuf, wreg, b_lin,
                                                 wreg + (size_t)Edim * DD, b2, tbuf);
    k_tr_bf<<<dim3((u32)(MD / 256)), dim3(256), 0, stream>>>(tbuf, out);
  } else if (ws_size >= xb_b + h_b + tf_b) {
    // Fallback: f32 weights reg-staged, f32 tbuf
    u16* hbuf   = (u16*)(base + xb_b);
    float* tbuf = (float*)(base + xb_b + h_b);
    k_h2<true><<<dim3(4800), dim3(256), 0, stream>>>(xb, w1, b1, hbuf, 0);
    k_out2<1, true><<<dim3(4800), dim3(256), 0, stream>>>(xb, hbuf, w_lin, b_lin, w2, b2,
                                                          (void*)tbuf, out, 0);
    k_tr_f32<<<dim3((u32)(MD / 128)), dim3(256), 0, stream>>>(tbuf, out);
  } else {
    // Chunked fallback: direct strided writes (slow but correct)
    size_t avail = ws_size > xb_b ? ws_size - xb_b : 0;
    int EC = (int)(avail / (MD * 2));
    if (EC < 1) EC = 1;
    if (EC > Edim) EC = Edim;
    u16* hbuf = (u16*)(base + xb_b);
    for (int e0 = 0; e0 < Edim; e0 += EC) {
      int ne = (Edim - e0) < EC ? (Edim - e0) : EC;
      k_h2<false><<<dim3(ne * 48), dim3(256), 0, stream>>>(xb, w1, b1, hbuf, e0);
      k_out2<2, false><<<dim3(ne * 48), dim3(256), 0, stream>>>(
          xb, hbuf, w_lin, b_lin, w2, b2, nullptr, out, e0);
    }
  }
}

// Round 5
// 774.563 us; speedup vs baseline: 1.2715x; 1.1715x over previous
//
#include <hip/hip_runtime.h>
#include <hip/hip_bf16.h>
#include <cstdint>

typedef __attribute__((ext_vector_type(8))) short short8;
typedef __attribute__((ext_vector_type(4))) float f32x4;
typedef unsigned short u16;
typedef unsigned int u32;

#define Mdim 1024
#define Ddim 768
#define Edim 100
#define DD (Ddim * Ddim)

__device__ __forceinline__ u16 f2bf(float f) {
  u32 u = __builtin_bit_cast(u32, f);
  u += 0x7fffu + ((u >> 16) & 1u);   // RNE
  return (u16)(u >> 16);
}
__device__ __forceinline__ float bf2f(u16 h) {
  return __builtin_bit_cast(float, ((u32)h) << 16);
}
__device__ __forceinline__ u32 pack2(float a, float b) {
  return (u32)f2bf(a) | ((u32)f2bf(b) << 16);
}

// async global->LDS, 16B per lane; lds dest is wave-uniform base + lane*16
#define GLL16(gsrc, ldst)                                                        \
  __builtin_amdgcn_global_load_lds(                                             \
      (const __attribute__((address_space(1))) u32*)(gsrc),                     \
      (__attribute__((address_space(3))) u32*)(ldst), 16, 0, 0)

#define VM8 asm volatile("s_waitcnt vmcnt(8)" ::: "memory")
#define VM0 asm volatile("s_waitcnt vmcnt(0)" ::: "memory")
#define RAW_BAR                                                                  \
  do {                                                                           \
    __builtin_amdgcn_s_barrier();                                                \
    asm volatile("" ::: "memory");                                               \
  } while (0)

// ---------------- x: f32 -> bf16 ----------------
__global__ void k_cvt(const float* __restrict__ x, u16* __restrict__ xb) {
  size_t i = ((size_t)blockIdx.x * 256 + threadIdx.x) * 4;
  float4 v = *(const float4*)(x + i);
  uint2 r;
  r.x = pack2(v.x, v.y);
  r.y = pack2(v.z, v.w);
  *(uint2*)(xb + i) = r;
}

// ---------------- weights: f32 -> bf16, grid-stride ----------------
__global__ __launch_bounds__(256) void k_cvtw(const float* __restrict__ w,
                                              u16* __restrict__ wb, int n8) {
  const int stride = gridDim.x * 256;
  for (int i = blockIdx.x * 256 + threadIdx.x; i < n8; i += stride) {
    const size_t o = (size_t)i * 8;
    const float4 f0 = *(const float4*)(w + o);
    const float4 f1 = *(const float4*)(w + o + 4);
    uint4 v;
    v.x = pack2(f0.x, f0.y); v.y = pack2(f0.z, f0.w);
    v.z = pack2(f1.x, f1.y); v.w = pack2(f1.z, f1.w);
    *(uint4*)(wb + o) = v;
  }
}

// =======================================================================
// 8-phase 256x256 GEMM core (m201-style), BK=64, 8 waves, wave tile 128x64.
// LDS 128KB: buf b at b*32768 elems (A 16384, then B 16384).
// Swizzle: LDS[row][slot'] holds global[row][slot' ^ (row&7)] (slots of 16B);
// staged via pre-swizzled global source (GLL16 dest linear), read with the
// same XOR -> conflict-free ds_read_b128.
// Ledger per K-tile T (buf T&1): reads A at p0,p1; B at p0,p2.
//   stage A(T+2) at p2 (A reads done by p1-end barrier),
//   stage B(T+2) at p3 (B reads done by p2-end barrier).
//   one vmcnt(8) per tile at p3 -> tile T+1 fully landed; 8 loads in flight.
// =======================================================================
template <int NT>
__device__ __forceinline__ void gemm8(const u16* __restrict__ A0,
                                      const u16* __restrict__ A1,
                                      const u16* __restrict__ B0,
                                      const u16* __restrict__ B1,
                                      u16* lds, f32x4 (&acc)[8][4], const int t) {
  const int w = t >> 6, l = t & 63;
  const int wr = (w >> 2) << 7;       // 0 / 128
  const int wc = (w & 3) << 6;        // 0..192
  const int lr = l & 15, c4 = l >> 4, r7 = l & 7;
  const int sl0 = ((c4 ^ r7) << 3);            // ks=0 slot offset (elems)
  const int sl1 = (((4 | c4) ^ r7) << 3);      // ks=1
  // staging: wave w covers rows w*32..w*32+31 (4 chunks of 8 rows), lane l ->
  // row +(l>>3), global col-slot (l&7)^(l>>3) (inverse swizzle).
  const size_t soff = (size_t)((w << 5) + (l >> 3)) * Ddim + (((l & 7) ^ (l >> 3)) << 3);

  auto stage_op = [&](const u16* src, int buf, int isB, int kk) {
    u16* d = lds + (buf << 15) + (isB << 14) + (w << 11);
    const u16* s = src + soff + (kk << 6);
#pragma unroll
    for (int i = 0; i < 4; ++i)
      GLL16(s + (size_t)(i << 3) * Ddim, d + (i << 9));
  };
  auto stage = [&](int tt, int isB) {
    const int buf = tt & 1;
    if (NT == 24 && tt >= 12) stage_op(isB ? B1 : A1, buf, isB, tt - 12);
    else                      stage_op(isB ? B0 : A0, buf, isB, tt);
  };

  short8 af[16], bf[4];
  auto rdA = [&](int buf, int half) {   // mf = half*4 .. +3 -> af[half*8 ..]
    const u16* ab = lds + (buf << 15) + (wr + (half << 6) + lr) * 64;
#pragma unroll
    for (int m = 0; m < 4; ++m) {
      af[half * 8 + m * 2]     = *(const short8*)(ab + (m << 10) + sl0);
      af[half * 8 + m * 2 + 1] = *(const short8*)(ab + (m << 10) + sl1);
    }
  };
  auto rdB = [&](int buf, int half) {   // nf = half*2 .. +1 -> bf[0..3]
    const u16* bb = lds + (buf << 15) + 16384 + (wc + (half << 5) + lr) * 64;
#pragma unroll
    for (int n = 0; n < 2; ++n) {
      bf[n * 2]     = *(const short8*)(bb + (n << 10) + sl0);
      bf[n * 2 + 1] = *(const short8*)(bb + (n << 10) + sl1);
    }
  };
  auto q = [&](int mh, int nh) {        // 16 MFMA: quadrant (mh, nh), ks0+ks1
    __builtin_amdgcn_s_setprio(1);
#pragma unroll
    for (int m = 0; m < 4; ++m)
#pragma unroll
      for (int n = 0; n < 2; ++n) {
        f32x4 c = acc[mh * 4 + m][nh * 2 + n];
        c = __builtin_amdgcn_mfma_f32_16x16x32_bf16(af[mh * 8 + m * 2],     bf[n * 2],     c, 0, 0, 0);
        c = __builtin_amdgcn_mfma_f32_16x16x32_bf16(af[mh * 8 + m * 2 + 1], bf[n * 2 + 1], c, 0, 0, 0);
        acc[mh * 4 + m][nh * 2 + n] = c;
      }
    __builtin_amdgcn_s_setprio(0);
  };

  // prologue: tiles 0,1 fully staged; tile 0 landed, tile 1 may fly
  stage(0, 1); stage(0, 0);
  stage(1, 1); stage(1, 0);
  VM8;
  RAW_BAR;

#pragma unroll 2
  for (int T = 0; T < NT - 2; ++T) {
    const int buf = T & 1;
    // p0
    rdA(buf, 0); rdB(buf, 0);
    RAW_BAR; q(0, 0); RAW_BAR;
    // p1
    rdA(buf, 1);
    RAW_BAR; q(1, 0); RAW_BAR;
    // p2: A reads of this tile finished at p1-end barrier -> stage A(T+2)
    rdB(buf, 1); stage(T + 2, 0);
    RAW_BAR; q(1, 1); RAW_BAR;
    // p3: B reads finished at p2-end barrier -> stage B(T+2)
    stage(T + 2, 1);
    VM8;                 // tile T+1 landed; tile T+2's 8 loads stay in flight
    RAW_BAR; q(0, 1); RAW_BAR;
  }
  {  // T = NT-2: no stages; drain at p3 so tile NT-1 is ready
    const int buf = (NT - 2) & 1;
    rdA(buf, 0); rdB(buf, 0); RAW_BAR; q(0, 0); RAW_BAR;
    rdA(buf, 1);              RAW_BAR; q(1, 0); RAW_BAR;
    rdB(buf, 1);              RAW_BAR; q(1, 1); RAW_BAR;
    VM0; RAW_BAR; q(0, 1); RAW_BAR;
  }
  {  // T = NT-1: pure compute
    const int buf = (NT - 1) & 1;
    rdA(buf, 0); rdB(buf, 0); RAW_BAR; q(0, 0); RAW_BAR;
    rdA(buf, 1);              RAW_BAR; q(1, 0); RAW_BAR;
    rdB(buf, 1);              RAW_BAR; q(1, 1); RAW_BAR;
    q(0, 1);
  }
}

// block decode: 1200 blocks = 100 experts x (4m x 3n); bijective XCD swizzle
// (1200 % 8 == 0) with expert-contiguous ordering per XCD.
__device__ __forceinline__ void decode8(int bid, int& e, int& m0, int& n0) {
  const int s = (bid & 7) * 150 + (bid >> 3);   // 0..1199
  e = s / 12;
  const int r = s % 12;
  m0 = (r & 3) << 8;
  n0 = (r >> 2) << 8;
}

// ---------------- kernel A: h = gelu(x @ w1^T + b1) ----------------
__global__ __launch_bounds__(512, 2) void k_h5(const u16* __restrict__ xb,
                                               const u16* __restrict__ w1b,
                                               const float* __restrict__ b1,
                                               u16* __restrict__ hout) {
  __shared__ __align__(16) u16 lds[65536];   // 128 KB
  int e, m0, n0;
  decode8(blockIdx.x, e, m0, n0);
  const int t = threadIdx.x;
  f32x4 acc[8][4] = {};
  gemm8<12>(xb + (size_t)m0 * Ddim, nullptr,
            w1b + (size_t)e * DD + (size_t)n0 * Ddim, nullptr, lds, acc, t);

  const int w = t >> 6, l = t & 63;
  const int wr = (w >> 2) << 7, wc = (w & 3) << 6;
  const int lr = l & 15, c4 = l >> 4;
  const float* bias = b1 + (size_t)e * Ddim + n0 + wc;
  u16* hb = hout + (size_t)e * Mdim * Ddim;
#pragma unroll
  for (int mf = 0; mf < 8; ++mf) {
    const int mb = m0 + wr + (mf << 4) + (c4 << 2);
#pragma unroll
    for (int nf = 0; nf < 4; ++nf) {
      const int nc = wc + (nf << 4) + lr;
      const float bv = bias[(nf << 4) + lr];
#pragma unroll
      for (int j = 0; j < 4; ++j) {
        float v = acc[mf][nf][j] + bv;
        v = 0.5f * v * (1.0f + erff(v * 0.7071067811865475f));
        hb[(size_t)(mb + j) * Ddim + n0 + nc] = f2bf(v);
      }
    }
  }
}

// ---------------- kernel B: x@wl^T + h@w2^T + biases -> bf16 tbuf ----------------
__global__ __launch_bounds__(512, 2) void k_out5(const u16* __restrict__ xb,
                                                 const u16* __restrict__ hbuf,
                                                 const u16* __restrict__ wlb,
                                                 const float* __restrict__ b_lin,
                                                 const u16* __restrict__ w2b,
                                                 const float* __restrict__ b2,
                                                 u16* __restrict__ tout) {
  __shared__ __align__(16) u16 lds[65536];   // 128 KB
  int e, m0, n0;
  decode8(blockIdx.x, e, m0, n0);
  const int t = threadIdx.x;
  f32x4 acc[8][4] = {};
  gemm8<24>(xb + (size_t)m0 * Ddim,
            hbuf + (size_t)e * Mdim * Ddim + (size_t)m0 * Ddim,
            wlb + (size_t)e * DD + (size_t)n0 * Ddim,
            w2b + (size_t)e * DD + (size_t)n0 * Ddim, lds, acc, t);

  const int w = t >> 6, l = t & 63;
  const int wr = (w >> 2) << 7, wc = (w & 3) << 6;
  const int lr = l & 15, c4 = l >> 4;
  const float* bl = b_lin + (size_t)e * Ddim + n0 + wc;
  const float* bm = b2 + (size_t)e * Ddim + n0 + wc;
#pragma unroll
  for (int mf = 0; mf < 8; ++mf) {
    const int mb = m0 + wr + (mf << 4) + (c4 << 2);
#pragma unroll
    for (int nf = 0; nf < 4; ++nf) {
      const int nc = wc + (nf << 4) + lr;
      const float bv = bl[(nf << 4) + lr] + bm[(nf << 4) + lr];
#pragma unroll
      for (int j = 0; j < 4; ++j) {
        float v = acc[mf][nf][j] + bv;
        tout[((size_t)e * Mdim + mb + j) * Ddim + n0 + nc] = f2bf(v);
      }
    }
  }
}

// ---------------- transpose [E][M*D] -> [M*D][E] (bf16 tbuf) ----------------
__global__ __launch_bounds__(256) void k_tr_bf(const u16* __restrict__ tbuf,
                                               float* __restrict__ out) {
  __shared__ __align__(16) u16 tile[100 * 260];
  const int t = threadIdx.x;
  const size_t MD = (size_t)Mdim * Ddim;
  const size_t md0 = (size_t)blockIdx.x * 256;
#pragma unroll
  for (int p = 0; p < 25; ++p) {
    const int e = p * 4 + (t >> 6);
    const int c = (t & 63) * 4;
    uint2 v = *(const uint2*)(tbuf + (size_t)e * MD + md0 + c);
    *(uint2*)(&tile[e * 260 + c]) = v;
  }
  __syncthreads();
  const size_t obase = md0 * 100;
#pragma unroll 5
  for (int i = 0; i < 100; ++i) {
    const int flat = t + i * 256;                     // < 25600
    const int mo = (int)(((u32)flat * 5243u) >> 19);  // /100
    const int e = flat - mo * 100;
    out[obase + flat] = bf2f(tile[e * 260 + mo]);
  }
}

// =======================================================================
// Legacy fallback (tiny workspace): f32 weights reg-staged, direct strided
// writes, chunked over experts. Slow but correct.
// =======================================================================
__device__ __forceinline__ void gemm_phase_f32(const u16* __restrict__ Ag,
                                               const float* __restrict__ Wg,
                                               u16* As, u16* Bs, f32x4 (&acc)[4][4], int t) {
  const int w = t >> 6, l = t & 63;
  const int lrow = l & 15, lk = (l >> 4) << 3;
  const int wr = ((w >> 1) << 6), wc = ((w & 1) << 6);
  for (int kt = 0; kt < Ddim; kt += 32) {
#pragma unroll
    for (int i = 0; i < 2; ++i) {
      GLL16(Ag + (size_t)((w << 5) + (i << 4) + (l >> 2)) * Ddim + kt + ((l & 3) << 3),
            As + (((w << 5) + (i << 4)) << 5));
    }
    {
      const int r = t >> 1, c = (t & 1) << 4;
      const float* src = Wg + (size_t)r * Ddim + kt + c;
      const float4 f0 = *(const float4*)(src);
      const float4 f1 = *(const float4*)(src + 4);
      const float4 f2 = *(const float4*)(src + 8);
      const float4 f3 = *(const float4*)(src + 12);
      uint4 v0, v1;
      v0.x = pack2(f0.x, f0.y); v0.y = pack2(f0.z, f0.w);
      v0.z = pack2(f1.x, f1.y); v0.w = pack2(f1.z, f1.w);
      v1.x = pack2(f2.x, f2.y); v1.y = pack2(f2.z, f2.w);
      v1.z = pack2(f3.x, f3.y); v1.w = pack2(f3.z, f3.w);
      *(uint4*)(&Bs[r * 32 + c]) = v0;
      *(uint4*)(&Bs[r * 32 + c + 8]) = v1;
    }
    __syncthreads();
    short8 af[4], bfr[4];
#pragma unroll
    for (int f = 0; f < 4; ++f) {
      af[f]  = *(const short8*)(&As[(wr + f * 16 + lrow) * 32 + lk]);
      bfr[f] = *(const short8*)(&Bs[(wc + f * 16 + lrow) * 32 + lk]);
    }
#pragma unroll
    for (int fm = 0; fm < 4; ++fm)
#pragma unroll
      for (int fn = 0; fn < 4; ++fn)
        acc[fm][fn] = __builtin_amdgcn_mfma_f32_16x16x32_bf16(af[fm], bfr[fn], acc[fm][fn], 0, 0, 0);
    __syncthreads();
  }
}

__global__ __launch_bounds__(256) void k_h2(const u16* __restrict__ xb,
                                            const float* __restrict__ w1,
                                            const float* __restrict__ b1,
                                            u16* __restrict__ hout, int e_base) {
  __shared__ __align__(16) u16 As[128 * 32];
  __shared__ __align__(16) u16 Bs[128 * 32];
  const int el = blockIdx.x / 48, r = blockIdx.x % 48;
  const int m0 = (r / 6) * 128, n0 = (r % 6) * 128;
  const int e = e_base + el;
  const int t = threadIdx.x, l = t & 63, wv = t >> 6;
  const int wr = (wv >> 1) * 64, wc = (wv & 1) * 64, lrow = l & 15;
  f32x4 acc[4][4] = {};
  gemm_phase_f32(xb + (size_t)m0 * Ddim, w1 + (size_t)e * DD + (size_t)n0 * Ddim, As, Bs, acc, t);
  const float* bias = b1 + (size_t)e * Ddim + n0;
  u16* hb = hout + (size_t)el * Mdim * Ddim;
#pragma unroll
  for (int fm = 0; fm < 4; ++fm) {
    const int mb = m0 + wr + fm * 16 + ((l >> 4) << 2);
#pragma unroll
    for (int fn = 0; fn < 4; ++fn) {
      const int nc = wc + fn * 16 + lrow;
      const float bv = bias[nc];
#pragma unroll
      for (int j = 0; j < 4; ++j) {
        float v = acc[fm][fn][j] + bv;
        v = 0.5f * v * (1.0f + erff(v * 0.7071067811865475f));
        hb[(size_t)(mb + j) * Ddim + n0 + nc] = f2bf(v);
      }
    }
  }
}

__global__ __launch_bounds__(256) void k_out2(
    const u16* __restrict__ xb, const u16* __restrict__ hbuf,
    const float* __restrict__ wl, const float* __restrict__ b_lin,
    const float* __restrict__ w2, const float* __restrict__ b2,
    float* __restrict__ out, int e_base) {
  __shared__ __align__(16) u16 As[128 * 32];
  __shared__ __align__(16) u16 Bs[128 * 32];
  const int el = blockIdx.x / 48, r = blockIdx.x % 48;
  const int m0 = (r / 6) * 128, n0 = (r % 6) * 128;
  const int e = e_base + el;
  const int t = threadIdx.x, l = t & 63, wv = t >> 6;
  const int wr = (wv >> 1) * 64, wc = (wv & 1) * 64, lrow = l & 15;
  f32x4 acc[4][4] = {};
  gemm_phase_f32(xb + (size_t)m0 * Ddim, wl + (size_t)e * DD + (size_t)n0 * Ddim, As, Bs, acc, t);
  gemm_phase_f32(hbuf + (size_t)el * Mdim * Ddim + (size_t)m0 * Ddim,
                 w2 + (size_t)e * DD + (size_t)n0 * Ddim, As, Bs, acc, t);
  const float* bl = b_lin + (size_t)e * Ddim + n0;
  const float* bm = b2 + (size_t)e * Ddim + n0;
#pragma unroll
  for (int fm = 0; fm < 4; ++fm) {
    const int mb = m0 + wr + fm * 16 + ((l >> 4) << 2);
#pragma unroll
    for (int fn = 0; fn < 4; ++fn) {
      const int nc = wc + fn * 16 + lrow;
      const float bv = bl[nc] + bm[nc];
#pragma unroll
      for (int j = 0; j < 4; ++j)
        out[((size_t)(mb + j) * Ddim + n0 + nc) * Edim + e] = acc[fm][fn][j] + bv;
    }
  }
}

extern "C" void kernel_launch(void* const* d_in, const int* in_sizes, int n_in,
                              void* d_out, int out_size, void* d_ws, size_t ws_size,
                              hipStream_t stream) {
  const float* x     = (const float*)d_in[0];
  const float* w_lin = (const float*)d_in[1];
  const float* b_lin = (const float*)d_in[2];
  const float* w1    = (const float*)d_in[3];
  const float* b1    = (const float*)d_in[4];
  const float* w2    = (const float*)d_in[5];
  const float* b2    = (const float*)d_in[6];
  float* out = (float*)d_out;

  const size_t MD = (size_t)Mdim * Ddim;          // 786432
  const size_t xb_b   = MD * 2;                   // 1.57 MB
  const size_t w1_b   = (size_t)Edim * DD * 2;    // 118 MB
  const size_t wreg_b = 2 * w1_b;                 // 236 MB
  const size_t h_b    = (size_t)Edim * MD * 2;    // 157 MB
  const size_t tb_b   = h_b;                      // 157 MB
  const int NW8 = (int)((size_t)Edim * DD / 8);   // 7,372,800

  char* base = (char*)d_ws;
  u16* xb = (u16*)base;
  k_cvt<<<dim3((u32)(MD / 1024)), dim3(256), 0, stream>>>(x, xb);

  if (ws_size >= xb_b + wreg_b + h_b + tb_b) {
    // Preferred: 8-phase 256x256 pipelined GEMMs + bf16 tbuf (552 MB)
    u16* wreg = (u16*)(base + xb_b);
    u16* hbuf = (u16*)(base + xb_b + wreg_b);
    u16* tbuf = (u16*)(base + xb_b + wreg_b + h_b);
    k_cvtw<<<dim3(2048), dim3(256), 0, stream>>>(w1, wreg, NW8);
    k_h5<<<dim3(1200), dim3(512), 0, stream>>>(xb, wreg, b1, hbuf);
    k_cvtw<<<dim3(2048), dim3(256), 0, stream>>>(w_lin, wreg, NW8);
    k_cvtw<<<dim3(2048), dim3(256), 0, stream>>>(w2, wreg + (size_t)Edim * DD, NW8);
    k_out5<<<dim3(1200), dim3(512), 0, stream>>>(xb, hbuf, wreg, b_lin,
                                                 wreg + (size_t)Edim * DD, b2, tbuf);
    k_tr_bf<<<dim3((u32)(MD / 256)), dim3(256), 0, stream>>>(tbuf, out);
  } else {
    // Chunked fallback: direct strided writes (slow but correct)
    size_t avail = ws_size > xb_b ? ws_size - xb_b : 0;
    int EC = (int)(avail / (MD * 2));
    if (EC < 1) EC = 1;
    if (EC > Edim) EC = Edim;
    u16* hbuf = (u16*)(base + xb_b);
    for (int e0 = 0; e0 < Edim; e0 += EC) {
      int ne = (Edim - e0) < EC ? (Edim - e0) : EC;
      k_h2<<<dim3(ne * 48), dim3(256), 0, stream>>>(xb, w1, b1, hbuf, e0);
      k_out2<<<dim3(ne * 48), dim3(256), 0, stream>>>(xb, hbuf, w_lin, b_lin, w2, b2,
                                                      out, e0);
    }
  }
}

// Round 6
// 705.187 us; speedup vs baseline: 1.3966x; 1.0984x over previous
//
#include <hip/hip_runtime.h>
#include <hip/hip_bf16.h>
#include <cstdint>

typedef __attribute__((ext_vector_type(8))) short short8;
typedef __attribute__((ext_vector_type(4))) float f32x4;
typedef unsigned short u16;
typedef unsigned int u32;

#define Mdim 1024
#define Ddim 768
#define Edim 100
#define DD (Ddim * Ddim)

__device__ __forceinline__ u16 f2bf(float f) {
  u32 u = __builtin_bit_cast(u32, f);
  u += 0x7fffu + ((u >> 16) & 1u);   // RNE
  return (u16)(u >> 16);
}
__device__ __forceinline__ float bf2f(u16 h) {
  return __builtin_bit_cast(float, ((u32)h) << 16);
}
__device__ __forceinline__ u32 pack2(float a, float b) {
  return (u32)f2bf(a) | ((u32)f2bf(b) << 16);
}

// fast GELU (tanh form): v - v / (1 + 2^(v*(c1 + c2 v^2)))
// c1 = 2*log2(e)*0.7978845608, c2 = c1*0.044715. |err vs erf-GELU| <~ 1e-3.
__device__ __forceinline__ float gelu_f(float v) {
  float v2 = v * v;
  float wv = v * (2.30220795f + 0.10294322f * v2);
  float ew = __builtin_amdgcn_exp2f(wv);
  return v - v * __builtin_amdgcn_rcpf(ew + 1.0f);
}

// async global->LDS, 16B per lane; lds dest is wave-uniform base + lane*16
#define GLL16(gsrc, ldst)                                                        \
  __builtin_amdgcn_global_load_lds(                                             \
      (const __attribute__((address_space(1))) u32*)(gsrc),                     \
      (__attribute__((address_space(3))) u32*)(ldst), 16, 0, 0)

#define VM8 asm volatile("s_waitcnt vmcnt(8)" ::: "memory")
#define VM0 asm volatile("s_waitcnt vmcnt(0)" ::: "memory")
#define LGKM0 asm volatile("s_waitcnt lgkmcnt(0)" ::: "memory")
#define RAW_BAR                                                                  \
  do {                                                                           \
    __builtin_amdgcn_s_barrier();                                                \
    asm volatile("" ::: "memory");                                               \
  } while (0)

// ---------------- x: f32 -> bf16 ----------------
__global__ void k_cvt(const float* __restrict__ x, u16* __restrict__ xb) {
  size_t i = ((size_t)blockIdx.x * 256 + threadIdx.x) * 4;
  float4 v = *(const float4*)(x + i);
  uint2 r;
  r.x = pack2(v.x, v.y);
  r.y = pack2(v.z, v.w);
  *(uint2*)(xb + i) = r;
}

// ---------------- weights: f32 -> bf16, grid-stride ----------------
__global__ __launch_bounds__(256) void k_cvtw(const float* __restrict__ w,
                                              u16* __restrict__ wb, int n8) {
  const int stride = gridDim.x * 256;
  for (int i = blockIdx.x * 256 + threadIdx.x; i < n8; i += stride) {
    const size_t o = (size_t)i * 8;
    const float4 f0 = *(const float4*)(w + o);
    const float4 f1 = *(const float4*)(w + o + 4);
    uint4 v;
    v.x = pack2(f0.x, f0.y); v.y = pack2(f0.z, f0.w);
    v.z = pack2(f1.x, f1.y); v.w = pack2(f1.z, f1.w);
    *(uint4*)(wb + o) = v;
  }
}

// =======================================================================
// 8-phase 256x256 GEMM core (unchanged from R5; verified).
// =======================================================================
template <int NT>
__device__ __forceinline__ void gemm8(const u16* __restrict__ A0,
                                      const u16* __restrict__ A1,
                                      const u16* __restrict__ B0,
                                      const u16* __restrict__ B1,
                                      u16* lds, f32x4 (&acc)[8][4], const int t) {
  const int w = t >> 6, l = t & 63;
  const int wr = (w >> 2) << 7;       // 0 / 128
  const int wc = (w & 3) << 6;        // 0..192
  const int lr = l & 15, c4 = l >> 4, r7 = l & 7;
  const int sl0 = ((c4 ^ r7) << 3);            // ks=0 slot offset (elems)
  const int sl1 = (((4 | c4) ^ r7) << 3);      // ks=1
  const size_t soff = (size_t)((w << 5) + (l >> 3)) * Ddim + (((l & 7) ^ (l >> 3)) << 3);

  auto stage_op = [&](const u16* src, int buf, int isB, int kk) {
    u16* d = lds + (buf << 15) + (isB << 14) + (w << 11);
    const u16* s = src + soff + (kk << 6);
#pragma unroll
    for (int i = 0; i < 4; ++i)
      GLL16(s + (size_t)(i << 3) * Ddim, d + (i << 9));
  };
  auto stage = [&](int tt, int isB) {
    const int buf = tt & 1;
    if (NT == 24 && tt >= 12) stage_op(isB ? B1 : A1, buf, isB, tt - 12);
    else                      stage_op(isB ? B0 : A0, buf, isB, tt);
  };

  short8 af[16], bf[4];
  auto rdA = [&](int buf, int half) {
    const u16* ab = lds + (buf << 15) + (wr + (half << 6) + lr) * 64;
#pragma unroll
    for (int m = 0; m < 4; ++m) {
      af[half * 8 + m * 2]     = *(const short8*)(ab + (m << 10) + sl0);
      af[half * 8 + m * 2 + 1] = *(const short8*)(ab + (m << 10) + sl1);
    }
  };
  auto rdB = [&](int buf, int half) {
    const u16* bb = lds + (buf << 15) + 16384 + (wc + (half << 5) + lr) * 64;
#pragma unroll
    for (int n = 0; n < 2; ++n) {
      bf[n * 2]     = *(const short8*)(bb + (n << 10) + sl0);
      bf[n * 2 + 1] = *(const short8*)(bb + (n << 10) + sl1);
    }
  };
  auto q = [&](int mh, int nh) {
    __builtin_amdgcn_s_setprio(1);
#pragma unroll
    for (int m = 0; m < 4; ++m)
#pragma unroll
      for (int n = 0; n < 2; ++n) {
        f32x4 c = acc[mh * 4 + m][nh * 2 + n];
        c = __builtin_amdgcn_mfma_f32_16x16x32_bf16(af[mh * 8 + m * 2],     bf[n * 2],     c, 0, 0, 0);
        c = __builtin_amdgcn_mfma_f32_16x16x32_bf16(af[mh * 8 + m * 2 + 1], bf[n * 2 + 1], c, 0, 0, 0);
        acc[mh * 4 + m][nh * 2 + n] = c;
      }
    __builtin_amdgcn_s_setprio(0);
  };

  stage(0, 1); stage(0, 0);
  stage(1, 1); stage(1, 0);
  VM8;
  RAW_BAR;

#pragma unroll 2
  for (int T = 0; T < NT - 2; ++T) {
    const int buf = T & 1;
    rdA(buf, 0); rdB(buf, 0);
    RAW_BAR; q(0, 0); RAW_BAR;
    rdA(buf, 1);
    RAW_BAR; q(1, 0); RAW_BAR;
    rdB(buf, 1); stage(T + 2, 0);
    RAW_BAR; q(1, 1); RAW_BAR;
    stage(T + 2, 1);
    VM8;
    RAW_BAR; q(0, 1); RAW_BAR;
  }
  {
    const int buf = (NT - 2) & 1;
    rdA(buf, 0); rdB(buf, 0); RAW_BAR; q(0, 0); RAW_BAR;
    rdA(buf, 1);              RAW_BAR; q(1, 0); RAW_BAR;
    rdB(buf, 1);              RAW_BAR; q(1, 1); RAW_BAR;
    VM0; RAW_BAR; q(0, 1); RAW_BAR;
  }
  {
    const int buf = (NT - 1) & 1;
    rdA(buf, 0); rdB(buf, 0); RAW_BAR; q(0, 0); RAW_BAR;
    rdA(buf, 1);              RAW_BAR; q(1, 0); RAW_BAR;
    rdB(buf, 1);              RAW_BAR; q(1, 1); RAW_BAR;
    q(0, 1);
  }
}

// =======================================================================
// Epilogue: frags -> (bias [+gelu]) -> bf16 -> wave-private LDS [128][64]
// (slot-XOR swizzle, conflict-free) -> 16x {ds_read_b128 + store_dwordx4}.
// Safe LDS reuse: lgkmcnt(0) + barrier first (all waves' K-loop reads retired).
// =======================================================================
template <bool GELU>
__device__ __forceinline__ void epi_store(f32x4 (&acc)[8][4], const float* bias,
                                          u16* lds, u16* gout, int m_base, int n_base,
                                          const int t) {
  const int w = t >> 6, l = t & 63;
  const int lr = l & 15, c4 = l >> 4;
  u16* reg = lds + (w << 13);   // wave-private 8192 u16 = 16 KB

  LGKM0;
  __builtin_amdgcn_sched_barrier(0);
  RAW_BAR;

  float bv[4];
#pragma unroll
  for (int nf = 0; nf < 4; ++nf) bv[nf] = bias[(nf << 4) + lr];

#pragma unroll
  for (int mf = 0; mf < 8; ++mf) {
#pragma unroll
    for (int nf = 0; nf < 4; ++nf) {
      const int slot = (nf << 1) + (lr >> 3);
      const int bis = (lr & 7);
#pragma unroll
      for (int j = 0; j < 4; ++j) {
        float v = acc[mf][nf][j] + bv[nf];
        if (GELU) v = gelu_f(v);
        const int row = (mf << 4) + (c4 << 2) + j;
        reg[row * 64 + ((slot ^ (row & 7)) << 3) + bis] = f2bf(v);
      }
    }
  }
  // flush: lane l, pass r -> row = r*8 + (l>>3), logical slot = l&7
  const int g = l >> 3;
  const int phys = ((l & 7) ^ g) << 3;   // row&7 == g for all r
#pragma unroll
  for (int r = 0; r < 16; ++r) {
    const int row = (r << 3) + g;
    short8 v = *(const short8*)(reg + row * 64 + phys);
    *(short8*)(gout + (size_t)(m_base + row) * Ddim + n_base + ((l & 7) << 3)) = v;
  }
}

// block decode: 1200 blocks = 100 experts x (4m x 3n); bijective XCD swizzle.
__device__ __forceinline__ void decode8(int bid, int& e, int& m0, int& n0) {
  const int s = (bid & 7) * 150 + (bid >> 3);   // 0..1199
  e = s / 12;
  const int r = s % 12;
  m0 = (r & 3) << 8;
  n0 = (r >> 2) << 8;
}

// ---------------- kernel A: h = gelu(x @ w1^T + b1) ----------------
__global__ __launch_bounds__(512, 2) void k_h6(const u16* __restrict__ xb,
                                               const u16* __restrict__ w1b,
                                               const float* __restrict__ b1,
                                               u16* __restrict__ hout) {
  __shared__ __align__(16) u16 lds[65536];   // 128 KB
  int e, m0, n0;
  decode8(blockIdx.x, e, m0, n0);
  const int t = threadIdx.x;
  f32x4 acc[8][4] = {};
  gemm8<12>(xb + (size_t)m0 * Ddim, nullptr,
            w1b + (size_t)e * DD + (size_t)n0 * Ddim, nullptr, lds, acc, t);

  const int w = t >> 6;
  const int wr = (w >> 2) << 7, wc = (w & 3) << 6;
  epi_store<true>(acc, b1 + (size_t)e * Ddim + n0 + wc, lds,
                  hout + (size_t)e * Mdim * Ddim, m0 + wr, n0 + wc, t);
}

// ---------------- kernel B: x@wl^T + h@w2^T + biases -> bf16 tbuf ----------------
__global__ __launch_bounds__(512, 2) void k_out6(const u16* __restrict__ xb,
                                                 const u16* __restrict__ hbuf,
                                                 const u16* __restrict__ wlb,
                                                 const float* __restrict__ b_lin,
                                                 const u16* __restrict__ w2b,
                                                 const float* __restrict__ b2,
                                                 u16* __restrict__ tout) {
  __shared__ __align__(16) u16 lds[65536];   // 128 KB
  int e, m0, n0;
  decode8(blockIdx.x, e, m0, n0);
  const int t = threadIdx.x;
  f32x4 acc[8][4] = {};
  gemm8<24>(xb + (size_t)m0 * Ddim,
            hbuf + (size_t)e * Mdim * Ddim + (size_t)m0 * Ddim,
            wlb + (size_t)e * DD + (size_t)n0 * Ddim,
            w2b + (size_t)e * DD + (size_t)n0 * Ddim, lds, acc, t);

  const int w = t >> 6, l = t & 63;
  const int wr = (w >> 2) << 7, wc = (w & 3) << 6;
  const int lr = l & 15;
  // combined bias into LDS-free local array via epi_store's bias pointer trick:
  // precompute bl+bm into registers then feed through a small stack array is
  // awkward; instead add bm into acc first, then pass bl as epilogue bias.
  const float* bm = b2 + (size_t)e * Ddim + n0 + wc;
#pragma unroll
  for (int nf = 0; nf < 4; ++nf) {
    const float bmv = bm[(nf << 4) + lr];
#pragma unroll
    for (int mf = 0; mf < 8; ++mf)
#pragma unroll
      for (int j = 0; j < 4; ++j) acc[mf][nf][j] += bmv;
  }
  epi_store<false>(acc, b_lin + (size_t)e * Ddim + n0 + wc, lds,
                   tout + (size_t)e * Mdim * Ddim, m0 + wr, n0 + wc, t);
}

// ---------------- transpose [E][M*D] -> [M*D][E] (bf16 tbuf) ----------------
__global__ __launch_bounds__(256) void k_tr_bf(const u16* __restrict__ tbuf,
                                               float* __restrict__ out) {
  __shared__ __align__(16) u16 tile[100 * 260];
  const int t = threadIdx.x;
  const size_t MD = (size_t)Mdim * Ddim;
  const size_t md0 = (size_t)blockIdx.x * 256;
#pragma unroll
  for (int p = 0; p < 25; ++p) {
    const int e = p * 4 + (t >> 6);
    const int c = (t & 63) * 4;
    uint2 v = *(const uint2*)(tbuf + (size_t)e * MD + md0 + c);
    *(uint2*)(&tile[e * 260 + c]) = v;
  }
  __syncthreads();
  const size_t obase = md0 * 100;
#pragma unroll 5
  for (int i = 0; i < 100; ++i) {
    const int flat = t + i * 256;                     // < 25600
    const int mo = (int)(((u32)flat * 5243u) >> 19);  // /100
    const int e = flat - mo * 100;
    out[obase + flat] = bf2f(tile[e * 260 + mo]);
  }
}

// =======================================================================
// Legacy fallback (tiny workspace): f32 weights reg-staged, direct strided
// writes, chunked over experts. Slow but correct.
// =======================================================================
__device__ __forceinline__ void gemm_phase_f32(const u16* __restrict__ Ag,
                                               const float* __restrict__ Wg,
                                               u16* As, u16* Bs, f32x4 (&acc)[4][4], int t) {
  const int w = t >> 6, l = t & 63;
  const int lrow = l & 15, lk = (l >> 4) << 3;
  const int wr = ((w >> 1) << 6), wc = ((w & 1) << 6);
  for (int kt = 0; kt < Ddim; kt += 32) {
#pragma unroll
    for (int i = 0; i < 2; ++i) {
      GLL16(Ag + (size_t)((w << 5) + (i << 4) + (l >> 2)) * Ddim + kt + ((l & 3) << 3),
            As + (((w << 5) + (i << 4)) << 5));
    }
    {
      const int r = t >> 1, c = (t & 1) << 4;
      const float* src = Wg + (size_t)r * Ddim + kt + c;
      const float4 f0 = *(const float4*)(src);
      const float4 f1 = *(const float4*)(src + 4);
      const float4 f2 = *(const float4*)(src + 8);
      const float4 f3 = *(const float4*)(src + 12);
      uint4 v0, v1;
      v0.x = pack2(f0.x, f0.y); v0.y = pack2(f0.z, f0.w);
      v0.z = pack2(f1.x, f1.y); v0.w = pack2(f1.z, f1.w);
      v1.x = pack2(f2.x, f2.y); v1.y = pack2(f2.z, f2.w);
      v1.z = pack2(f3.x, f3.y); v1.w = pack2(f3.z, f3.w);
      *(uint4*)(&Bs[r * 32 + c]) = v0;
      *(uint4*)(&Bs[r * 32 + c + 8]) = v1;
    }
    __syncthreads();
    short8 af[4], bfr[4];
#pragma unroll
    for (int f = 0; f < 4; ++f) {
      af[f]  = *(const short8*)(&As[(wr + f * 16 + lrow) * 32 + lk]);
      bfr[f] = *(const short8*)(&Bs[(wc + f * 16 + lrow) * 32 + lk]);
    }
#pragma unroll
    for (int fm = 0; fm < 4; ++fm)
#pragma unroll
      for (int fn = 0; fn < 4; ++fn)
        acc[fm][fn] = __builtin_amdgcn_mfma_f32_16x16x32_bf16(af[fm], bfr[fn], acc[fm][fn], 0, 0, 0);
    __syncthreads();
  }
}

__global__ __launch_bounds__(256) void k_h2(const u16* __restrict__ xb,
                                            const float* __restrict__ w1,
                                            const float* __restrict__ b1,
                                            u16* __restrict__ hout, int e_base) {
  __shared__ __align__(16) u16 As[128 * 32];
  __shared__ __align__(16) u16 Bs[128 * 32];
  const int el = blockIdx.x / 48, r = blockIdx.x % 48;
  const int m0 = (r / 6) * 128, n0 = (r % 6) * 128;
  const int e = e_base + el;
  const int t = threadIdx.x, l = t & 63, wv = t >> 6;
  const int wr = (wv >> 1) * 64, wc = (wv & 1) * 64, lrow = l & 15;
  f32x4 acc[4][4] = {};
  gemm_phase_f32(xb + (size_t)m0 * Ddim, w1 + (size_t)e * DD + (size_t)n0 * Ddim, As, Bs, acc, t);
  const float* bias = b1 + (size_t)e * Ddim + n0;
  u16* hb = hout + (size_t)el * Mdim * Ddim;
#pragma unroll
  for (int fm = 0; fm < 4; ++fm) {
    const int mb = m0 + wr + fm * 16 + ((l >> 4) << 2);
#pragma unroll
    for (int fn = 0; fn < 4; ++fn) {
      const int nc = wc + fn * 16 + lrow;
      const float bv = bias[nc];
#pragma unroll
      for (int j = 0; j < 4; ++j) {
        float v = acc[fm][fn][j] + bv;
        v = 0.5f * v * (1.0f + erff(v * 0.7071067811865475f));
        hb[(size_t)(mb + j) * Ddim + n0 + nc] = f2bf(v);
      }
    }
  }
}

__global__ __launch_bounds__(256) void k_out2(
    const u16* __restrict__ xb, const u16* __restrict__ hbuf,
    const float* __restrict__ wl, const float* __restrict__ b_lin,
    const float* __restrict__ w2, const float* __restrict__ b2,
    float* __restrict__ out, int e_base) {
  __shared__ __align__(16) u16 As[128 * 32];
  __shared__ __align__(16) u16 Bs[128 * 32];
  const int el = blockIdx.x / 48, r = blockIdx.x % 48;
  const int m0 = (r / 6) * 128, n0 = (r % 6) * 128;
  const int e = e_base + el;
  const int t = threadIdx.x, l = t & 63, wv = t >> 6;
  const int wr = (wv >> 1) * 64, wc = (wv & 1) * 64, lrow = l & 15;
  f32x4 acc[4][4] = {};
  gemm_phase_f32(xb + (size_t)m0 * Ddim, wl + (size_t)e * DD + (size_t)n0 * Ddim, As, Bs, acc, t);
  gemm_phase_f32(hbuf + (size_t)el * Mdim * Ddim + (size_t)m0 * Ddim,
                 w2 + (size_t)e * DD + (size_t)n0 * Ddim, As, Bs, acc, t);
  const float* bl = b_lin + (size_t)e * Ddim + n0;
  const float* bm = b2 + (size_t)e * Ddim + n0;
#pragma unroll
  for (int fm = 0; fm < 4; ++fm) {
    const int mb = m0 + wr + fm * 16 + ((l >> 4) << 2);
#pragma unroll
    for (int fn = 0; fn < 4; ++fn) {
      const int nc = wc + fn * 16 + lrow;
      const float bv = bl[nc] + bm[nc];
#pragma unroll
      for (int j = 0; j < 4; ++j)
        out[((size_t)(mb + j) * Ddim + n0 + nc) * Edim + e] = acc[fm][fn][j] + bv;
    }
  }
}

extern "C" void kernel_launch(void* const* d_in, const int* in_sizes, int n_in,
                              void* d_out, int out_size, void* d_ws, size_t ws_size,
                              hipStream_t stream) {
  const float* x     = (const float*)d_in[0];
  const float* w_lin = (const float*)d_in[1];
  const float* b_lin = (const float*)d_in[2];
  const float* w1    = (const float*)d_in[3];
  const float* b1    = (const float*)d_in[4];
  const float* w2    = (const float*)d_in[5];
  const float* b2    = (const float*)d_in[6];
  float* out = (float*)d_out;

  const size_t MD = (size_t)Mdim * Ddim;          // 786432
  const size_t xb_b   = MD * 2;                   // 1.57 MB
  const size_t w1_b   = (size_t)Edim * DD * 2;    // 118 MB
  const size_t wreg_b = 2 * w1_b;                 // 236 MB
  const size_t h_b    = (size_t)Edim * MD * 2;    // 157 MB
  const size_t tb_b   = h_b;                      // 157 MB
  const int NW8 = (int)((size_t)Edim * DD / 8);   // 7,372,800

  char* base = (char*)d_ws;
  u16* xb = (u16*)base;
  k_cvt<<<dim3((u32)(MD / 1024)), dim3(256), 0, stream>>>(x, xb);

  if (ws_size >= xb_b + wreg_b + h_b + tb_b) {
    // Preferred: 8-phase 256x256 pipelined GEMMs + bf16 tbuf (552 MB)
    u16* wreg = (u16*)(base + xb_b);
    u16* hbuf = (u16*)(base + xb_b + wreg_b);
    u16* tbuf = (u16*)(base + xb_b + wreg_b + h_b);
    k_cvtw<<<dim3(2048), dim3(256), 0, stream>>>(w1, wreg, NW8);
    k_h6<<<dim3(1200), dim3(512), 0, stream>>>(xb, wreg, b1, hbuf);
    k_cvtw<<<dim3(2048), dim3(256), 0, stream>>>(w_lin, wreg, NW8);
    k_cvtw<<<dim3(2048), dim3(256), 0, stream>>>(w2, wreg + (size_t)Edim * DD, NW8);
    k_out6<<<dim3(1200), dim3(512), 0, stream>>>(xb, hbuf, wreg, b_lin,
                                                 wreg + (size_t)Edim * DD, b2, tbuf);
    k_tr_bf<<<dim3((u32)(MD / 256)), dim3(256), 0, stream>>>(tbuf, out);
  } else {
    // Chunked fallback: direct strided writes (slow but correct)
    size_t avail = ws_size > xb_b ? ws_size - xb_b : 0;
    int EC = (int)(avail / (MD * 2));
    if (EC < 1) EC = 1;
    if (EC > Edim) EC = Edim;
    u16* hbuf = (u16*)(base + xb_b);
    for (int e0 = 0; e0 < Edim; e0 += EC) {
      int ne = (Edim - e0) < EC ? (Edim - e0) : EC;
      k_h2<<<dim3(ne * 48), dim3(256), 0, stream>>>(xb, w1, b1, hbuf, e0);
      k_out2<<<dim3(ne * 48), dim3(256), 0, stream>>>(xb, hbuf, w_lin, b_lin, w2, b2,
                                                      out, e0);
    }
  }
}